// Round 1
// baseline (371.553 us; speedup 1.0000x reference)
//
#include <hip/hip_runtime.h>
#include <math.h>

#define NB 32
#define LL 512
#define HH 1024
#define H2 512
#define DA 64

// ---------------- LayerNorm over v = x[..., 512:1024] ----------------
__global__ void ln_kernel(const float* __restrict__ x,
                          const float* __restrict__ gamma,
                          const float* __restrict__ beta,
                          float* __restrict__ vn) {
    int row = blockIdx.x;                       // b*L + l
    const float* vr = x + (size_t)row * HH + H2;
    int t = threadIdx.x;                        // 0..255
    float a0 = vr[t], a1 = vr[t + 256];
    float s = a0 + a1, ss = a0 * a0 + a1 * a1;
#pragma unroll
    for (int off = 32; off > 0; off >>= 1) {
        s  += __shfl_down(s, off);
        ss += __shfl_down(ss, off);
    }
    __shared__ float ws[4], wss[4], stats[2];
    int wave = t >> 6;
    if ((t & 63) == 0) { ws[wave] = s; wss[wave] = ss; }
    __syncthreads();
    if (t == 0) {
        float S  = ws[0] + ws[1] + ws[2] + ws[3];
        float SS = wss[0] + wss[1] + wss[2] + wss[3];
        float mu  = S * (1.0f / H2);
        float var = SS * (1.0f / H2) - mu * mu;
        stats[0] = mu; stats[1] = rsqrtf(var + 1e-5f);
    }
    __syncthreads();
    float mu = stats[0], rstd = stats[1];
    float* o = vn + (size_t)row * H2;
    o[t]       = (a0 - mu) * rstd * gamma[t]       + beta[t];
    o[t + 256] = (a1 - mu) * rstd * gamma[t + 256] + beta[t + 256];
}

// ---------------- kqv = v @ W[512,192] + b ----------------
// C[16384,192]; v[r,k] = x[r*1024 + 512 + k]
__global__ void kqv_kernel(const float* __restrict__ x,
                           const float* __restrict__ W,
                           const float* __restrict__ bias,
                           float* __restrict__ kqv) {
    const int N = 3 * DA;                       // 192
    __shared__ float As[16][64];                // As[k][m]
    __shared__ float Bs[16][64];                // Bs[k][n]
    int r0 = blockIdx.x * 64;
    int n0 = blockIdx.y * 64;
    int t = threadIdx.x;
    int tx = t & 15, ty = t >> 4;
    float acc[4][4] = {};
    int lm = t >> 2, lk4 = (t & 3) * 4;         // A-load mapping (float4 along k)
    int bk = t >> 4, bn4 = (t & 15) * 4;        // B-load mapping (float4 along n)
    for (int k0 = 0; k0 < H2; k0 += 16) {
        float4 av = *(const float4*)(x + (size_t)(r0 + lm) * HH + H2 + k0 + lk4);
        As[lk4 + 0][lm] = av.x; As[lk4 + 1][lm] = av.y;
        As[lk4 + 2][lm] = av.z; As[lk4 + 3][lm] = av.w;
        *(float4*)&Bs[bk][bn4] = *(const float4*)(W + (size_t)(k0 + bk) * N + n0 + bn4);
        __syncthreads();
#pragma unroll
        for (int k = 0; k < 16; ++k) {
            float a[4], b[4];
#pragma unroll
            for (int i = 0; i < 4; ++i) a[i] = As[k][ty * 4 + i];
#pragma unroll
            for (int j = 0; j < 4; ++j) b[j] = Bs[k][tx * 4 + j];
#pragma unroll
            for (int i = 0; i < 4; ++i)
#pragma unroll
                for (int j = 0; j < 4; ++j)
                    acc[i][j] += a[i] * b[j];
        }
        __syncthreads();
    }
#pragma unroll
    for (int i = 0; i < 4; ++i) {
        int r = r0 + ty * 4 + i;
#pragma unroll
        for (int j = 0; j < 4; ++j) {
            int n = n0 + tx * 4 + j;
            kqv[(size_t)r * N + n] = acc[i][j] + bias[n];
        }
    }
}

// ---------------- flash-style tiny attention ----------------
// kqv rows: [k(0:64) | q(64:128) | v(128:192)]; head[b,l,64]
__global__ void attn_kernel(const float* __restrict__ kqv,
                            float* __restrict__ head) {
    const int N = 3 * DA;
    int b  = blockIdx.y;
    int q0 = blockIdx.x * 32;
    int t  = threadIdx.x;
    __shared__ float Qs[32][68];
    __shared__ float Ks[32][68];
    __shared__ float Vs[32][68];
    __shared__ float S[32][36];
    __shared__ float mrow[32], lrow[32], arow[32];

    const float* base = kqv + (size_t)b * LL * N;
    for (int s = t; s < 512; s += 256) {        // 512 float4 slots (32 rows x 16)
        int qi = s >> 4, d4 = (s & 15) * 4;
        *(float4*)&Qs[qi][d4] = *(const float4*)(base + (size_t)(q0 + qi) * N + DA + d4);
    }
    if (t < 32) { mrow[t] = -1e30f; lrow[t] = 0.0f; }
    int qi = t >> 3;                            // 0..31
    int dg = t & 7;                             // dims dg*8 .. dg*8+7
    float o[8] = {0, 0, 0, 0, 0, 0, 0, 0};
    const float scale = 0.125f;

    for (int kc = 0; kc < LL; kc += 32) {
        __syncthreads();                        // protect Ks/Vs/S from prev readers, publish Qs
        for (int s = t; s < 512; s += 256) {
            int ki = s >> 4, d4 = (s & 15) * 4;
            *(float4*)&Ks[ki][d4] = *(const float4*)(base + (size_t)(kc + ki) * N + 0 + d4);
            *(float4*)&Vs[ki][d4] = *(const float4*)(base + (size_t)(kc + ki) * N + 2 * DA + d4);
        }
        __syncthreads();
        {   // scores: thread handles (qi, 4 kj)
            int kjb = (t & 7) * 4;
            float sc[4] = {0, 0, 0, 0};
#pragma unroll 8
            for (int d = 0; d < 64; ++d) {
                float qv = Qs[qi][d];
#pragma unroll
                for (int jj = 0; jj < 4; ++jj)
                    sc[jj] += qv * Ks[kjb + jj][d];
            }
#pragma unroll
            for (int jj = 0; jj < 4; ++jj)
                S[qi][kjb + jj] = sc[jj] * scale;
        }
        __syncthreads();
        if (t < 32) {                           // online-softmax state update, 1 thread/row
            float m_old = mrow[t];
            float cm = m_old;
            for (int j = 0; j < 32; ++j) cm = fmaxf(cm, S[t][j]);
            float alpha = __expf(m_old - cm);
            float cs = 0.0f;
            for (int j = 0; j < 32; ++j) {
                float p = __expf(S[t][j] - cm);
                S[t][j] = p;
                cs += p;
            }
            mrow[t] = cm;
            lrow[t] = lrow[t] * alpha + cs;
            arow[t] = alpha;
        }
        __syncthreads();
        float alpha = arow[qi];
#pragma unroll
        for (int d = 0; d < 8; ++d) o[d] *= alpha;
#pragma unroll 4
        for (int kj = 0; kj < 32; ++kj) {
            float p = S[qi][kj];
            const float* vv = &Vs[kj][dg * 8];
#pragma unroll
            for (int d = 0; d < 8; ++d) o[d] += p * vv[d];
        }
    }
    __syncthreads();
    float inv = 1.0f / lrow[qi];
    float* hp = head + (size_t)(b * LL + q0 + qi) * DA + dg * 8;
#pragma unroll
    for (int d = 0; d < 8; ++d) hp[d] = o[d] * inv;
}

// ---------------- fused Toeplitz GEMM + proj + bias + gate ----------------
// out[b,m,c] = u[b,m,c] * ( sum_l vn[b,l,c]*wv[511+m-l] + sum_d head[b,m,d]*projw[d,c]
//                           + projb[c] + tbias[m] )
#define MLD 68
__global__ void mix_kernel(const float* __restrict__ x,
                           const float* __restrict__ vn,
                           const float* __restrict__ wv,     // [1023]
                           const float* __restrict__ tbias,  // [512]
                           const float* __restrict__ head,   // [B,L,64]
                           const float* __restrict__ projw,  // [64,512]
                           const float* __restrict__ projb,  // [512]
                           float* __restrict__ out) {
    __shared__ __align__(16) float smem[2 * 64 * MLD];       // reused: (Ws,Cs) then (Hs,Ps)
    float* Ws = smem;                // [16][MLD]  Ws[k][m] = wv[511 + m0+m - (l0+k)]
    float* Cs = smem + 16 * MLD;     // [16][MLD]  Cs[k][c] = vn[b, l0+k, c0+c]
    int b  = blockIdx.z;
    int m0 = blockIdx.y * 64;
    int c0 = blockIdx.x * 64;
    int t  = threadIdx.x;
    int tx = t & 15, ty = t >> 4;
    float acc[4][4] = {};
    int wk = t >> 4, wm4 = (t & 15) * 4;
    const float* vnb = vn + (size_t)b * LL * H2;
    for (int l0 = 0; l0 < LL; l0 += 16) {
        int basei = 511 + m0 + wm4 - l0 - wk;
        Ws[wk * MLD + wm4 + 0] = wv[basei + 0];
        Ws[wk * MLD + wm4 + 1] = wv[basei + 1];
        Ws[wk * MLD + wm4 + 2] = wv[basei + 2];
        Ws[wk * MLD + wm4 + 3] = wv[basei + 3];
        *(float4*)&Cs[wk * MLD + wm4] =
            *(const float4*)(vnb + (size_t)(l0 + wk) * H2 + c0 + wm4);
        __syncthreads();
#pragma unroll
        for (int k = 0; k < 16; ++k) {
            float a[4], bb[4];
#pragma unroll
            for (int i = 0; i < 4; ++i) a[i] = Ws[k * MLD + ty * 4 + i];
#pragma unroll
            for (int j = 0; j < 4; ++j) bb[j] = Cs[k * MLD + tx * 4 + j];
#pragma unroll
            for (int i = 0; i < 4; ++i)
#pragma unroll
                for (int j = 0; j < 4; ++j)
                    acc[i][j] += a[i] * bb[j];
        }
        __syncthreads();
    }
    // epilogue: proj(head) tile as mini-GEMM in LDS
    float* Hs = smem;                // [64][MLD]  Hs[m][d]
    float* Ps = smem + 64 * MLD;     // [64][MLD]  Ps[d][c]
    for (int s = t; s < 1024; s += 256) {
        int r = s >> 4, c4 = (s & 15) * 4;
        *(float4*)&Hs[r * MLD + c4] =
            *(const float4*)(head + (size_t)(b * LL + m0 + r) * DA + c4);
        *(float4*)&Ps[r * MLD + c4] =
            *(const float4*)(projw + (size_t)r * H2 + c0 + c4);
    }
    __syncthreads();
    float pr[4][4] = {};
#pragma unroll 4
    for (int d = 0; d < 64; ++d) {
        float a[4], p[4];
#pragma unroll
        for (int i = 0; i < 4; ++i) a[i] = Hs[(ty * 4 + i) * MLD + d];
#pragma unroll
        for (int j = 0; j < 4; ++j) p[j] = Ps[d * MLD + tx * 4 + j];
#pragma unroll
        for (int i = 0; i < 4; ++i)
#pragma unroll
            for (int j = 0; j < 4; ++j)
                pr[i][j] += a[i] * p[j];
    }
#pragma unroll
    for (int i = 0; i < 4; ++i) {
        int m = m0 + ty * 4 + i;
        const float* urow = x + (size_t)(b * LL + m) * HH;
        float tb = tbias[m];
#pragma unroll
        for (int j = 0; j < 4; ++j) {
            int c = c0 + tx * 4 + j;
            float val = acc[i][j] + pr[i][j] + projb[c] + tb;
            out[(size_t)(b * LL + m) * H2 + c] = urow[c] * val;
        }
    }
}

extern "C" void kernel_launch(void* const* d_in, const int* in_sizes, int n_in,
                              void* d_out, int out_size, void* d_ws, size_t ws_size,
                              hipStream_t stream) {
    (void)in_sizes; (void)n_in; (void)out_size; (void)ws_size;
    const float* x     = (const float*)d_in[0];
    const float* gamma = (const float*)d_in[1];
    const float* beta  = (const float*)d_in[2];
    const float* wv    = (const float*)d_in[3];
    const float* tb    = (const float*)d_in[4];
    const float* kqvw  = (const float*)d_in[5];
    const float* kqvb  = (const float*)d_in[6];
    const float* projw = (const float*)d_in[7];
    const float* projb = (const float*)d_in[8];
    float* out = (float*)d_out;

    float* vn   = (float*)d_ws;                     // [B*L*512]  32 MB
    float* kqv  = vn  + (size_t)NB * LL * H2;       // [B*L*192]  12 MB
    float* head = kqv + (size_t)NB * LL * 3 * DA;   // [B*L*64]    4 MB

    ln_kernel  <<<NB * LL, 256, 0, stream>>>(x, gamma, beta, vn);
    kqv_kernel <<<dim3(NB * LL / 64, 3), 256, 0, stream>>>(x, kqvw, kqvb, kqv);
    attn_kernel<<<dim3(LL / 32, NB), 256, 0, stream>>>(kqv, head);
    mix_kernel <<<dim3(8, 8, NB), 256, 0, stream>>>(x, vn, wv, tb, head, projw, projb, out);
}

// Round 2
// 254.226 us; speedup vs baseline: 1.4615x; 1.4615x over previous
//
#include <hip/hip_runtime.h>
#include <math.h>

#define NB 32
#define LL 512
#define HH 1024
#define H2 512
#define DA 64

typedef unsigned int u32;
typedef unsigned short u16;
typedef __bf16 bf16x8 __attribute__((ext_vector_type(8)));
typedef float f32x4 __attribute__((ext_vector_type(4)));

__device__ __forceinline__ u16 f2bu(float f) {          // fp32 -> bf16 bits, RNE
    u32 u = __builtin_bit_cast(u32, f);
    u = (u + 0x7fff + ((u >> 16) & 1)) >> 16;
    return (u16)u;
}

__device__ __forceinline__ void async_cp16(const void* g, void* l) {
    __builtin_amdgcn_global_load_lds(
        (const __attribute__((address_space(1))) u32*)g,
        (__attribute__((address_space(3))) u32*)l, 16, 0, 0);
}

// ---------------- prep: bf16 weight materialization ----------------
// wt[m][l] = wv[511+m-l]; kqvwT[n][k] = kqvw[k][n]; projwT[c][d] = projw[d][c]
__global__ void prep_kernel(const float* __restrict__ wv,
                            const float* __restrict__ kqvw,
                            const float* __restrict__ projw,
                            u16* __restrict__ wt, u16* __restrict__ kqvwT,
                            u16* __restrict__ projwT) {
    int e = blockIdx.x * 256 + threadIdx.x;
    if (e < 262144) {
        int m = e >> 9, l = e & 511;
        wt[e] = f2bu(wv[511 + m - l]);
    } else if (e < 262144 + 98304) {
        int i = e - 262144;
        int n = i >> 9, k = i & 511;
        kqvwT[i] = f2bu(kqvw[(size_t)k * 192 + n]);
    } else {
        int i = e - 360448;
        int c = i >> 6, d = i & 63;
        projwT[i] = f2bu(projw[(size_t)d * 512 + c]);
    }
}

// ---------------- LayerNorm over v = x[..., 512:1024] -> bf16 ----------------
__global__ void ln_kernel(const float* __restrict__ x,
                          const float* __restrict__ gamma,
                          const float* __restrict__ beta,
                          u16* __restrict__ vn) {
    int row = blockIdx.x;                       // b*L + l
    const float* vr = x + (size_t)row * HH + H2;
    int t = threadIdx.x;                        // 0..255
    float a0 = vr[t], a1 = vr[t + 256];
    float s = a0 + a1, ss = a0 * a0 + a1 * a1;
#pragma unroll
    for (int off = 32; off > 0; off >>= 1) {
        s  += __shfl_down(s, off);
        ss += __shfl_down(ss, off);
    }
    __shared__ float ws[4], wss[4], stats[2];
    int wave = t >> 6;
    if ((t & 63) == 0) { ws[wave] = s; wss[wave] = ss; }
    __syncthreads();
    if (t == 0) {
        float S  = ws[0] + ws[1] + ws[2] + ws[3];
        float SS = wss[0] + wss[1] + wss[2] + wss[3];
        float mu  = S * (1.0f / H2);
        float var = SS * (1.0f / H2) - mu * mu;
        stats[0] = mu; stats[1] = rsqrtf(var + 1e-5f);
    }
    __syncthreads();
    float mu = stats[0], rstd = stats[1];
    u16* o = vn + (size_t)row * H2;
    o[t]       = f2bu((a0 - mu) * rstd * gamma[t]       + beta[t]);
    o[t + 256] = f2bu((a1 - mu) * rstd * gamma[t + 256] + beta[t + 256]);
}

// ---------------- bf16 transpose: vn [b][l][c] -> vnT [b][c][l] ----------------
__global__ void transpose_kernel(const u16* __restrict__ in, u16* __restrict__ outT) {
    __shared__ u16 T[64][65];
    int b = blockIdx.z, l0 = blockIdx.y * 64, c0 = blockIdx.x * 64;
    int t = threadIdx.x;
#pragma unroll
    for (int s = 0; s < 4; ++s) {
        int ci = t + s * 256;
        int row = ci >> 4, c4 = (ci & 15) * 4;
        ushort4 v = *(const ushort4*)(in + ((size_t)(b * LL + l0 + row)) * H2 + c0 + c4);
        T[c4 + 0][row] = v.x; T[c4 + 1][row] = v.y;
        T[c4 + 2][row] = v.z; T[c4 + 3][row] = v.w;
    }
    __syncthreads();
#pragma unroll
    for (int s = 0; s < 4; ++s) {
        int ci = t + s * 256;
        int c = ci >> 4, l4 = (ci & 15) * 4;
        ushort4 w;
        w.x = T[c][l4 + 0]; w.y = T[c][l4 + 1];
        w.z = T[c][l4 + 2]; w.w = T[c][l4 + 3];
        *(ushort4*)(outT + ((size_t)(b * H2 + c0 + c)) * LL + l0 + l4) = w;
    }
}

// ---------------- kqv = v @ W[512,192] + b  (bf16 MFMA) ----------------
__global__ __launch_bounds__(256, 2)
void kqv_kernel(const float* __restrict__ x, const u16* __restrict__ wT,
                const float* __restrict__ bias, float* __restrict__ kqv) {
    __shared__ u16 As[64 * 32];
    __shared__ u16 Bs[192 * 32];
    int r0 = blockIdx.x * 64;
    int t = threadIdx.x, lane = t & 63, wid = t >> 6;
    int wm = (wid >> 1) * 32, wn = (wid & 1) * 96;
    int l15 = lane & 15, q8 = (lane >> 4) * 8;
    f32x4 acc[2][6] = {};
    for (int k0 = 0; k0 < 512; k0 += 32) {
#pragma unroll
        for (int s = 0; s < 3; ++s) {          // B: 192x32 bf16 = 768 x 16B chunks
            int ci = t + s * 256;
            async_cp16(wT + (size_t)(ci >> 2) * 512 + k0 + (ci & 3) * 8, Bs + ci * 8);
        }
#pragma unroll
        for (int s = 0; s < 2; ++s) {          // A: 64x32 fp32->bf16, 512 x 4-elem chunks
            int ci = t + s * 256;
            int row = ci >> 3, c4 = (ci & 7) * 4;
            float4 v = *(const float4*)(x + (size_t)(r0 + row) * HH + H2 + k0 + c4);
            ushort4 p;
            p.x = f2bu(v.x); p.y = f2bu(v.y); p.z = f2bu(v.z); p.w = f2bu(v.w);
            *(ushort4*)(As + row * 32 + c4) = p;
        }
        __syncthreads();
        bf16x8 a[2], bb[6];
#pragma unroll
        for (int i = 0; i < 2; ++i)
            a[i] = *(const bf16x8*)(As + (wm + i * 16 + l15) * 32 + q8);
#pragma unroll
        for (int j = 0; j < 6; ++j)
            bb[j] = *(const bf16x8*)(Bs + (wn + j * 16 + l15) * 32 + q8);
#pragma unroll
        for (int i = 0; i < 2; ++i)
#pragma unroll
            for (int j = 0; j < 6; ++j)
                acc[i][j] = __builtin_amdgcn_mfma_f32_16x16x32_bf16(a[i], bb[j], acc[i][j], 0, 0, 0);
        __syncthreads();
    }
    int rq = (lane >> 4) * 4;
#pragma unroll
    for (int i = 0; i < 2; ++i)
#pragma unroll
        for (int r = 0; r < 4; ++r) {
            int m = r0 + wm + i * 16 + rq + r;
#pragma unroll
            for (int j = 0; j < 6; ++j) {
                int n = wn + j * 16 + l15;
                kqv[(size_t)m * 192 + n] = acc[i][j][r] + bias[n];
            }
        }
}

// ---------------- flash-style tiny attention (fp32, head out bf16) ----------------
__global__ void attn_kernel(const float* __restrict__ kqv,
                            u16* __restrict__ head) {
    const int N = 3 * DA;
    int b  = blockIdx.y;
    int q0 = blockIdx.x * 32;
    int t  = threadIdx.x;
    __shared__ float Qs[32][68];
    __shared__ float Ks[32][68];
    __shared__ float Vs[32][68];
    __shared__ float S[32][36];
    __shared__ float mrow[32], lrow[32], arow[32];

    const float* base = kqv + (size_t)b * LL * N;
    for (int s = t; s < 512; s += 256) {
        int qi = s >> 4, d4 = (s & 15) * 4;
        *(float4*)&Qs[qi][d4] = *(const float4*)(base + (size_t)(q0 + qi) * N + DA + d4);
    }
    if (t < 32) { mrow[t] = -1e30f; lrow[t] = 0.0f; }
    int qi = t >> 3;
    int dg = t & 7;
    float o[8] = {0, 0, 0, 0, 0, 0, 0, 0};
    const float scale = 0.125f;

    for (int kc = 0; kc < LL; kc += 32) {
        __syncthreads();
        for (int s = t; s < 512; s += 256) {
            int ki = s >> 4, d4 = (s & 15) * 4;
            *(float4*)&Ks[ki][d4] = *(const float4*)(base + (size_t)(kc + ki) * N + 0 + d4);
            *(float4*)&Vs[ki][d4] = *(const float4*)(base + (size_t)(kc + ki) * N + 2 * DA + d4);
        }
        __syncthreads();
        {
            int kjb = (t & 7) * 4;
            float sc[4] = {0, 0, 0, 0};
#pragma unroll 8
            for (int d = 0; d < 64; ++d) {
                float qv = Qs[qi][d];
#pragma unroll
                for (int jj = 0; jj < 4; ++jj)
                    sc[jj] += qv * Ks[kjb + jj][d];
            }
#pragma unroll
            for (int jj = 0; jj < 4; ++jj)
                S[qi][kjb + jj] = sc[jj] * scale;
        }
        __syncthreads();
        if (t < 32) {
            float m_old = mrow[t];
            float cm = m_old;
            for (int j = 0; j < 32; ++j) cm = fmaxf(cm, S[t][j]);
            float alpha = __expf(m_old - cm);
            float cs = 0.0f;
            for (int j = 0; j < 32; ++j) {
                float p = __expf(S[t][j] - cm);
                S[t][j] = p;
                cs += p;
            }
            mrow[t] = cm;
            lrow[t] = lrow[t] * alpha + cs;
            arow[t] = alpha;
        }
        __syncthreads();
        float alpha = arow[qi];
#pragma unroll
        for (int d = 0; d < 8; ++d) o[d] *= alpha;
#pragma unroll 4
        for (int kj = 0; kj < 32; ++kj) {
            float p = S[qi][kj];
            const float* vv = &Vs[kj][dg * 8];
#pragma unroll
            for (int d = 0; d < 8; ++d) o[d] += p * vv[d];
        }
    }
    __syncthreads();
    float inv = 1.0f / lrow[qi];
    u16* hp = head + (size_t)(b * LL + q0 + qi) * DA + dg * 8;
#pragma unroll
    for (int d = 0; d < 8; ++d) hp[d] = f2bu(o[d] * inv);
}

// ---------------- fused Toeplitz GEMM + proj + bias + gate (bf16 MFMA) ----------------
__device__ __forceinline__ void mfma_step(const u16* As, const u16* Bs,
                                          f32x4 acc[4][4], int wm, int wn, int lane) {
    int l15 = lane & 15, q8 = (lane >> 4) * 8;
    bf16x8 a[4], bv[4];
#pragma unroll
    for (int i = 0; i < 4; ++i)
        a[i] = *(const bf16x8*)(As + (wm + i * 16 + l15) * 32 + q8);
#pragma unroll
    for (int j = 0; j < 4; ++j)
        bv[j] = *(const bf16x8*)(Bs + (wn + j * 16 + l15) * 32 + q8);
#pragma unroll
    for (int i = 0; i < 4; ++i)
#pragma unroll
        for (int j = 0; j < 4; ++j)
            acc[i][j] = __builtin_amdgcn_mfma_f32_16x16x32_bf16(a[i], bv[j], acc[i][j], 0, 0, 0);
}

__global__ __launch_bounds__(256, 2)
void mix_kernel(const u16* __restrict__ wt,      // [512 m][512 l]
                const u16* __restrict__ vnT,     // [B][512 c][512 l]
                const u16* __restrict__ headb,   // [B][512 m][64 d]
                const u16* __restrict__ projwT,  // [512 c][64 d]
                const float* __restrict__ x,
                const float* __restrict__ tbias,
                const float* __restrict__ projb,
                float* __restrict__ out) {
    __shared__ u16 As[128 * 32];
    __shared__ u16 Bs[128 * 32];
    int b = blockIdx.z, m0 = blockIdx.y * 128, c0 = blockIdx.x * 128;
    int t = threadIdx.x, lane = t & 63, wid = t >> 6;
    int wm = (wid >> 1) * 64, wn = (wid & 1) * 64;
    f32x4 acc[4][4] = {};
    int ci0 = t, ci1 = t + 256;                  // 512 x 16B chunks per tile
    int r0a = ci0 >> 2, s0a = (ci0 & 3) * 8;
    int r1a = ci1 >> 2, s1a = (ci1 & 3) * 8;
    const u16* Ag = wt + (size_t)m0 * 512;
    const u16* Bg = vnT + ((size_t)b * H2 + c0) * 512;
    for (int k0 = 0; k0 < 512; k0 += 32) {       // Toeplitz phase: K = 512
        async_cp16(Ag + (size_t)r0a * 512 + k0 + s0a, As + ci0 * 8);
        async_cp16(Ag + (size_t)r1a * 512 + k0 + s1a, As + ci1 * 8);
        async_cp16(Bg + (size_t)r0a * 512 + k0 + s0a, Bs + ci0 * 8);
        async_cp16(Bg + (size_t)r1a * 512 + k0 + s1a, Bs + ci1 * 8);
        __syncthreads();
        mfma_step(As, Bs, acc, wm, wn, lane);
        __syncthreads();
    }
    const u16* Hg = headb + ((size_t)b * LL + m0) * DA;
    const u16* Pg = projwT + (size_t)c0 * DA;
    for (int k0 = 0; k0 < 64; k0 += 32) {        // proj phase: K = 64, same accumulators
        async_cp16(Hg + (size_t)r0a * 64 + k0 + s0a, As + ci0 * 8);
        async_cp16(Hg + (size_t)r1a * 64 + k0 + s1a, As + ci1 * 8);
        async_cp16(Pg + (size_t)r0a * 64 + k0 + s0a, Bs + ci0 * 8);
        async_cp16(Pg + (size_t)r1a * 64 + k0 + s1a, Bs + ci1 * 8);
        __syncthreads();
        mfma_step(As, Bs, acc, wm, wn, lane);
        __syncthreads();
    }
    int l15 = lane & 15, rq = (lane >> 4) * 4;
#pragma unroll
    for (int i = 0; i < 4; ++i) {
#pragma unroll
        for (int r = 0; r < 4; ++r) {
            int m = m0 + wm + i * 16 + rq + r;
            float tb = tbias[m];
            const float* xrow = x + ((size_t)b * LL + m) * HH;
            float* orow = out + ((size_t)b * LL + m) * H2;
#pragma unroll
            for (int j = 0; j < 4; ++j) {
                int c = c0 + wn + j * 16 + l15;
                float val = acc[i][j][r] + tb + projb[c];
                orow[c] = xrow[c] * val;
            }
        }
    }
}

extern "C" void kernel_launch(void* const* d_in, const int* in_sizes, int n_in,
                              void* d_out, int out_size, void* d_ws, size_t ws_size,
                              hipStream_t stream) {
    (void)in_sizes; (void)n_in; (void)out_size; (void)ws_size;
    const float* x     = (const float*)d_in[0];
    const float* gamma = (const float*)d_in[1];
    const float* beta  = (const float*)d_in[2];
    const float* wv    = (const float*)d_in[3];
    const float* tb    = (const float*)d_in[4];
    const float* kqvw  = (const float*)d_in[5];
    const float* kqvb  = (const float*)d_in[6];
    const float* projw = (const float*)d_in[7];
    const float* projb = (const float*)d_in[8];
    float* out = (float*)d_out;

    // workspace layout (46.75 MB total)
    u16*   vn_bf   = (u16*)d_ws;                           // 16 MB
    u16*   vnT_bf  = vn_bf + (size_t)NB * LL * H2;         // 16 MB
    float* kqv     = (float*)(vnT_bf + (size_t)NB * LL * H2); // 12 MB
    u16*   head_bf = (u16*)(kqv + (size_t)NB * LL * 3 * DA);  // 2 MB
    u16*   wt_bf   = head_bf + (size_t)NB * LL * DA;       // 512 KB
    u16*   kqvwT   = wt_bf + 512 * 512;                    // 192 KB
    u16*   projwT  = kqvwT + 192 * 512;                    // 64 KB

    prep_kernel     <<<1536, 256, 0, stream>>>(wv, kqvw, projw, wt_bf, kqvwT, projwT);
    ln_kernel       <<<NB * LL, 256, 0, stream>>>(x, gamma, beta, vn_bf);
    transpose_kernel<<<dim3(8, 8, NB), 256, 0, stream>>>(vn_bf, vnT_bf);
    kqv_kernel      <<<NB * LL / 64, 256, 0, stream>>>(x, kqvwT, kqvb, kqv);
    attn_kernel     <<<dim3(LL / 32, NB), 256, 0, stream>>>(kqv, head_bf);
    mix_kernel      <<<dim3(4, 4, NB), 256, 0, stream>>>(wt_bf, vnT_bf, head_bf, projwT, x, tb, projb, out);
}

// Round 3
// 192.709 us; speedup vs baseline: 1.9281x; 1.3192x over previous
//
#include <hip/hip_runtime.h>
#include <math.h>

#define NB 32
#define LL 512
#define HH 1024
#define H2 512
#define DA 64

typedef unsigned int u32;
typedef unsigned short u16;
typedef __bf16 bf16x8 __attribute__((ext_vector_type(8)));
typedef float f32x4 __attribute__((ext_vector_type(4)));

__device__ __forceinline__ u16 f2bu(float f) {          // fp32 -> bf16 bits, RNE
    u32 u = __builtin_bit_cast(u32, f);
    u = (u + 0x7fff + ((u >> 16) & 1)) >> 16;
    return (u16)u;
}

__device__ __forceinline__ void async_cp16(const void* g, void* l) {
    __builtin_amdgcn_global_load_lds(
        (const __attribute__((address_space(1))) u32*)g,
        (__attribute__((address_space(3))) u32*)l, 16, 0, 0);
}

// ---------------- prep: bf16 weight materialization ----------------
__global__ void prep_kernel(const float* __restrict__ wv,
                            const float* __restrict__ kqvw,
                            const float* __restrict__ projw,
                            u16* __restrict__ wt, u16* __restrict__ kqvwT,
                            u16* __restrict__ projwT) {
    int e = blockIdx.x * 256 + threadIdx.x;
    if (e < 262144) {
        int m = e >> 9, l = e & 511;
        wt[e] = f2bu(wv[511 + m - l]);
    } else if (e < 262144 + 98304) {
        int i = e - 262144;
        int n = i >> 9, k = i & 511;
        kqvwT[i] = f2bu(kqvw[(size_t)k * 192 + n]);
    } else {
        int i = e - 360448;
        int c = i >> 6, d = i & 63;
        projwT[i] = f2bu(projw[(size_t)d * 512 + c]);
    }
}

// ---------------- LayerNorm over v = x[..., 512:1024] -> bf16 ----------------
__global__ void ln_kernel(const float* __restrict__ x,
                          const float* __restrict__ gamma,
                          const float* __restrict__ beta,
                          u16* __restrict__ vn) {
    int row = blockIdx.x;
    const float* vr = x + (size_t)row * HH + H2;
    int t = threadIdx.x;
    float a0 = vr[t], a1 = vr[t + 256];
    float s = a0 + a1, ss = a0 * a0 + a1 * a1;
#pragma unroll
    for (int off = 32; off > 0; off >>= 1) {
        s  += __shfl_down(s, off);
        ss += __shfl_down(ss, off);
    }
    __shared__ float ws[4], wss[4], stats[2];
    int wave = t >> 6;
    if ((t & 63) == 0) { ws[wave] = s; wss[wave] = ss; }
    __syncthreads();
    if (t == 0) {
        float S  = ws[0] + ws[1] + ws[2] + ws[3];
        float SS = wss[0] + wss[1] + wss[2] + wss[3];
        float mu  = S * (1.0f / H2);
        float var = SS * (1.0f / H2) - mu * mu;
        stats[0] = mu; stats[1] = rsqrtf(var + 1e-5f);
    }
    __syncthreads();
    float mu = stats[0], rstd = stats[1];
    u16* o = vn + (size_t)row * H2;
    o[t]       = f2bu((a0 - mu) * rstd * gamma[t]       + beta[t]);
    o[t + 256] = f2bu((a1 - mu) * rstd * gamma[t + 256] + beta[t + 256]);
}

// ---------------- bf16 transpose: vn [b][l][c] -> vnT [b][c][l] ----------------
__global__ void transpose_kernel(const u16* __restrict__ in, u16* __restrict__ outT) {
    __shared__ u16 T[64][65];
    int b = blockIdx.z, l0 = blockIdx.y * 64, c0 = blockIdx.x * 64;
    int t = threadIdx.x;
#pragma unroll
    for (int s = 0; s < 4; ++s) {
        int ci = t + s * 256;
        int row = ci >> 4, c4 = (ci & 15) * 4;
        ushort4 v = *(const ushort4*)(in + ((size_t)(b * LL + l0 + row)) * H2 + c0 + c4);
        T[c4 + 0][row] = v.x; T[c4 + 1][row] = v.y;
        T[c4 + 2][row] = v.z; T[c4 + 3][row] = v.w;
    }
    __syncthreads();
#pragma unroll
    for (int s = 0; s < 4; ++s) {
        int ci = t + s * 256;
        int c = ci >> 4, l4 = (ci & 15) * 4;
        ushort4 w;
        w.x = T[c][l4 + 0]; w.y = T[c][l4 + 1];
        w.z = T[c][l4 + 2]; w.w = T[c][l4 + 3];
        *(ushort4*)(outT + ((size_t)(b * H2 + c0 + c)) * LL + l0 + l4) = w;
    }
}

// ---------------- kqv MFMA: writes bf16 q, k (row-major) and vT (transposed) ----------------
__global__ __launch_bounds__(256, 2)
void kqv_kernel(const float* __restrict__ x, const u16* __restrict__ wT,
                const float* __restrict__ bias,
                u16* __restrict__ qb, u16* __restrict__ kb, u16* __restrict__ vT) {
    __shared__ u16 smem[8192];                  // As[64*32] | Bs[192*32]; reused as Ts[64][68]
    u16* As = smem;
    u16* Bs = smem + 2048;
    int r0 = blockIdx.x * 64;
    int t = threadIdx.x, lane = t & 63, wid = t >> 6;
    int wm = (wid >> 1) * 32, wn = (wid & 1) * 96;
    int l15 = lane & 15, q16 = lane >> 4, q8 = q16 * 8;
    f32x4 acc[2][6] = {};
    for (int k0 = 0; k0 < 512; k0 += 32) {
#pragma unroll
        for (int s = 0; s < 3; ++s) {
            int ci = t + s * 256;
            async_cp16(wT + (size_t)(ci >> 2) * 512 + k0 + (ci & 3) * 8, Bs + ci * 8);
        }
#pragma unroll
        for (int s = 0; s < 2; ++s) {
            int ci = t + s * 256;
            int row = ci >> 3, c4 = (ci & 7) * 4;
            float4 v = *(const float4*)(x + (size_t)(r0 + row) * HH + H2 + k0 + c4);
            ushort4 p;
            p.x = f2bu(v.x); p.y = f2bu(v.y); p.z = f2bu(v.z); p.w = f2bu(v.w);
            *(ushort4*)(As + row * 32 + c4) = p;
        }
        __syncthreads();
        bf16x8 a[2], bb[6];
#pragma unroll
        for (int i = 0; i < 2; ++i)
            a[i] = *(const bf16x8*)(As + (wm + i * 16 + l15) * 32 + q8);
#pragma unroll
        for (int j = 0; j < 6; ++j)
            bb[j] = *(const bf16x8*)(Bs + (wn + j * 16 + l15) * 32 + q8);
#pragma unroll
        for (int i = 0; i < 2; ++i)
#pragma unroll
            for (int j = 0; j < 6; ++j)
                acc[i][j] = __builtin_amdgcn_mfma_f32_16x16x32_bf16(a[i], bb[j], acc[i][j], 0, 0, 0);
        __syncthreads();
    }
    // epilogue: k -> kb, q -> qb, v -> Ts (LDS transpose) -> vT
    u16* Ts = smem;                             // [64][68]
    int bb2 = r0 >> 9, l0loc = r0 & 511;
    int rq = q16 * 4;
#pragma unroll
    for (int i = 0; i < 2; ++i)
#pragma unroll
        for (int r = 0; r < 4; ++r) {
            int mloc = wm + i * 16 + rq + r;
            size_t mg = (size_t)(r0 + mloc);
#pragma unroll
            for (int j = 0; j < 6; ++j) {
                int n = wn + j * 16 + l15;
                u16 hv = f2bu(acc[i][j][r] + bias[n]);
                if (n < 64)       kb[mg * 64 + n] = hv;
                else if (n < 128) qb[mg * 64 + (n - 64)] = hv;
                else              Ts[(n - 128) * 68 + mloc] = hv;
            }
        }
    __syncthreads();
    int d = t >> 2, mo = (t & 3) * 16;
    u16* dst = vT + ((size_t)(bb2 * 64 + d)) * 512 + l0loc + mo;
    const u16* srcl = Ts + d * 68 + mo;
#pragma unroll
    for (int c = 0; c < 4; ++c)
        ((ushort4*)dst)[c] = ((const ushort4*)srcl)[c];
}

// ---------------- MFMA flash attention, split-K across 4 waves ----------------
// grid (32 q-tiles, 32 batches), 256 threads. Wave w: q-tile 16 rows, keys [128w,128w+128)
#define VLD 136
__global__ __launch_bounds__(256, 4)
void attn_kernel(const u16* __restrict__ qb, const u16* __restrict__ kb,
                 const u16* __restrict__ vT, u16* __restrict__ head) {
    __shared__ u16 Ps[4 * 16 * VLD];            // per-wave P, row-major [q][key], 17.4 KB
    __shared__ float Osh[4][16 * 65];           // per-wave O, 16.6 KB
    __shared__ float Msh[4][16], Lsh[4][16];
    int b = blockIdx.y, q0 = blockIdx.x * 16;
    int t = threadIdx.x, lane = t & 63, w = t >> 6;
    int l15 = lane & 15, q16 = lane >> 4, q8 = q16 * 8;
    int kc = w * 128;
    const u16* qg = qb + (size_t)b * LL * DA;
    const u16* kg = kb + (size_t)b * LL * DA;
    const u16* vg = vT + (size_t)b * DA * LL;

    // Q fragments (A-operand): rows q0+l15, k = s*32 + q16*8
    bf16x8 aq[2];
#pragma unroll
    for (int s = 0; s < 2; ++s)
        aq[s] = *(const bf16x8*)(qg + (size_t)(q0 + l15) * DA + s * 32 + q8);

    // S = Q K^T  (m=q, n=key), K b-frags straight from global
    f32x4 sc[8] = {};
#pragma unroll
    for (int j = 0; j < 8; ++j) {
#pragma unroll
        for (int s = 0; s < 2; ++s) {
            bf16x8 bk = *(const bf16x8*)(kg + (size_t)(kc + j * 16 + l15) * DA + s * 32 + q8);
            sc[j] = __builtin_amdgcn_mfma_f32_16x16x32_bf16(aq[s], bk, sc[j], 0, 0, 0);
        }
    }
    // scale + per-wave softmax (full chunk, no online rescale needed)
    float mx[4], sm[4];
#pragma unroll
    for (int j = 0; j < 8; ++j)
#pragma unroll
        for (int r = 0; r < 4; ++r) sc[j][r] *= 0.125f;
#pragma unroll
    for (int r = 0; r < 4; ++r) {
        float m0 = sc[0][r];
#pragma unroll
        for (int j = 1; j < 8; ++j) m0 = fmaxf(m0, sc[j][r]);
        m0 = fmaxf(m0, __shfl_xor(m0, 1));
        m0 = fmaxf(m0, __shfl_xor(m0, 2));
        m0 = fmaxf(m0, __shfl_xor(m0, 4));
        m0 = fmaxf(m0, __shfl_xor(m0, 8));
        mx[r] = m0;
    }
#pragma unroll
    for (int j = 0; j < 8; ++j)
#pragma unroll
        for (int r = 0; r < 4; ++r) sc[j][r] = __expf(sc[j][r] - mx[r]);
#pragma unroll
    for (int r = 0; r < 4; ++r) {
        float s0 = sc[0][r];
#pragma unroll
        for (int j = 1; j < 8; ++j) s0 += sc[j][r];
        s0 += __shfl_xor(s0, 1);
        s0 += __shfl_xor(s0, 2);
        s0 += __shfl_xor(s0, 4);
        s0 += __shfl_xor(s0, 8);
        sm[r] = s0;
    }
    // P -> LDS (C-layout -> row-major [q][key]) for A-operand reads
    u16* Pw = Ps + w * 16 * VLD;
#pragma unroll
    for (int j = 0; j < 8; ++j)
#pragma unroll
        for (int r = 0; r < 4; ++r)
            Pw[(q16 * 4 + r) * VLD + j * 16 + l15] = f2bu(sc[j][r]);
    // O = P V   (m=q, n=d), V^T b-frags straight from global
    f32x4 o[4] = {};
#pragma unroll
    for (int kt = 0; kt < 4; ++kt) {
        bf16x8 ap = *(const bf16x8*)(Pw + l15 * VLD + kt * 32 + q8);
#pragma unroll
        for (int j = 0; j < 4; ++j) {
            bf16x8 bv = *(const bf16x8*)(vg + (size_t)(j * 16 + l15) * LL + kc + kt * 32 + q8);
            o[j] = __builtin_amdgcn_mfma_f32_16x16x32_bf16(ap, bv, o[j], 0, 0, 0);
        }
    }
    // publish per-wave partials
#pragma unroll
    for (int j = 0; j < 4; ++j)
#pragma unroll
        for (int r = 0; r < 4; ++r)
            Osh[w][(q16 * 4 + r) * 65 + j * 16 + l15] = o[j][r];
    if (l15 == 0) {
#pragma unroll
        for (int r = 0; r < 4; ++r) {
            Msh[w][q16 * 4 + r] = mx[r];
            Lsh[w][q16 * 4 + r] = sm[r];
        }
    }
    __syncthreads();
    // flash combine: thread t -> q = t>>4, d = (t&15)*4 .. +3
    int q = t >> 4, dg = (t & 15) * 4;
    float m0 = Msh[0][q], m1 = Msh[1][q], m2 = Msh[2][q], m3 = Msh[3][q];
    float ms = fmaxf(fmaxf(m0, m1), fmaxf(m2, m3));
    float f0 = __expf(m0 - ms), f1 = __expf(m1 - ms), f2 = __expf(m2 - ms), f3 = __expf(m3 - ms);
    float lst = Lsh[0][q] * f0 + Lsh[1][q] * f1 + Lsh[2][q] * f2 + Lsh[3][q] * f3;
    float inv = 1.0f / lst;
    ushort4 res;
    u16* rp = (u16*)&res;
#pragma unroll
    for (int i = 0; i < 4; ++i) {
        int idx = q * 65 + dg + i;
        float a = Osh[0][idx] * f0 + Osh[1][idx] * f1 + Osh[2][idx] * f2 + Osh[3][idx] * f3;
        rp[i] = f2bu(a * inv);
    }
    *(ushort4*)(head + (size_t)(b * LL + q0 + q) * DA + dg) = res;
}

// ---------------- fused Toeplitz GEMM + proj + bias + gate (bf16 MFMA) ----------------
__device__ __forceinline__ void mfma_step(const u16* As, const u16* Bs,
                                          f32x4 acc[4][4], int wm, int wn, int lane) {
    int l15 = lane & 15, q8 = (lane >> 4) * 8;
    bf16x8 a[4], bv[4];
#pragma unroll
    for (int i = 0; i < 4; ++i)
        a[i] = *(const bf16x8*)(As + (wm + i * 16 + l15) * 32 + q8);
#pragma unroll
    for (int j = 0; j < 4; ++j)
        bv[j] = *(const bf16x8*)(Bs + (wn + j * 16 + l15) * 32 + q8);
#pragma unroll
    for (int i = 0; i < 4; ++i)
#pragma unroll
        for (int j = 0; j < 4; ++j)
            acc[i][j] = __builtin_amdgcn_mfma_f32_16x16x32_bf16(a[i], bv[j], acc[i][j], 0, 0, 0);
}

__global__ __launch_bounds__(256, 2)
void mix_kernel(const u16* __restrict__ wt,      // [512 m][512 l]
                const u16* __restrict__ vnT,     // [B][512 c][512 l]
                const u16* __restrict__ headb,   // [B][512 m][64 d]
                const u16* __restrict__ projwT,  // [512 c][64 d]
                const float* __restrict__ x,
                const float* __restrict__ tbias,
                const float* __restrict__ projb,
                float* __restrict__ out) {
    __shared__ u16 As[128 * 32];
    __shared__ u16 Bs[128 * 32];
    int b = blockIdx.z, m0 = blockIdx.y * 128, c0 = blockIdx.x * 128;
    int t = threadIdx.x, lane = t & 63, wid = t >> 6;
    int wm = (wid >> 1) * 64, wn = (wid & 1) * 64;
    f32x4 acc[4][4] = {};
    int ci0 = t, ci1 = t + 256;
    int r0a = ci0 >> 2, s0a = (ci0 & 3) * 8;
    int r1a = ci1 >> 2, s1a = (ci1 & 3) * 8;
    const u16* Ag = wt + (size_t)m0 * 512;
    const u16* Bg = vnT + ((size_t)b * H2 + c0) * 512;
    for (int k0 = 0; k0 < 512; k0 += 32) {
        async_cp16(Ag + (size_t)r0a * 512 + k0 + s0a, As + ci0 * 8);
        async_cp16(Ag + (size_t)r1a * 512 + k0 + s1a, As + ci1 * 8);
        async_cp16(Bg + (size_t)r0a * 512 + k0 + s0a, Bs + ci0 * 8);
        async_cp16(Bg + (size_t)r1a * 512 + k0 + s1a, Bs + ci1 * 8);
        __syncthreads();
        mfma_step(As, Bs, acc, wm, wn, lane);
        __syncthreads();
    }
    const u16* Hg = headb + ((size_t)b * LL + m0) * DA;
    const u16* Pg = projwT + (size_t)c0 * DA;
    for (int k0 = 0; k0 < 64; k0 += 32) {
        async_cp16(Hg + (size_t)r0a * 64 + k0 + s0a, As + ci0 * 8);
        async_cp16(Hg + (size_t)r1a * 64 + k0 + s1a, As + ci1 * 8);
        async_cp16(Pg + (size_t)r0a * 64 + k0 + s0a, Bs + ci0 * 8);
        async_cp16(Pg + (size_t)r1a * 64 + k0 + s1a, Bs + ci1 * 8);
        __syncthreads();
        mfma_step(As, Bs, acc, wm, wn, lane);
        __syncthreads();
    }
    int l15 = lane & 15, rq = (lane >> 4) * 4;
#pragma unroll
    for (int i = 0; i < 4; ++i) {
#pragma unroll
        for (int r = 0; r < 4; ++r) {
            int m = m0 + wm + i * 16 + rq + r;
            float tb = tbias[m];
            const float* xrow = x + ((size_t)b * LL + m) * HH;
            float* orow = out + ((size_t)b * LL + m) * H2;
#pragma unroll
            for (int j = 0; j < 4; ++j) {
                int c = c0 + wn + j * 16 + l15;
                float val = acc[i][j][r] + tb + projb[c];
                orow[c] = xrow[c] * val;
            }
        }
    }
}

extern "C" void kernel_launch(void* const* d_in, const int* in_sizes, int n_in,
                              void* d_out, int out_size, void* d_ws, size_t ws_size,
                              hipStream_t stream) {
    (void)in_sizes; (void)n_in; (void)out_size; (void)ws_size;
    const float* x     = (const float*)d_in[0];
    const float* gamma = (const float*)d_in[1];
    const float* beta  = (const float*)d_in[2];
    const float* wv    = (const float*)d_in[3];
    const float* tb    = (const float*)d_in[4];
    const float* kqvw  = (const float*)d_in[5];
    const float* kqvb  = (const float*)d_in[6];
    const float* projw = (const float*)d_in[7];
    const float* projb = (const float*)d_in[8];
    float* out = (float*)d_out;

    u16* vn_bf   = (u16*)d_ws;                          // 16 MB
    u16* vnT_bf  = vn_bf + (size_t)NB * LL * H2;        // 16 MB
    u16* qb      = vnT_bf + (size_t)NB * LL * H2;       // 2 MB
    u16* kb      = qb + (size_t)NB * LL * DA;           // 2 MB
    u16* vTb     = kb + (size_t)NB * LL * DA;           // 2 MB
    u16* head_bf = vTb + (size_t)NB * LL * DA;          // 2 MB
    u16* wt_bf   = head_bf + (size_t)NB * LL * DA;      // 512 KB
    u16* kqvwT   = wt_bf + 512 * 512;                   // 192 KB
    u16* projwT  = kqvwT + 192 * 512;                   // 64 KB

    prep_kernel     <<<1536, 256, 0, stream>>>(wv, kqvw, projw, wt_bf, kqvwT, projwT);
    ln_kernel       <<<NB * LL, 256, 0, stream>>>(x, gamma, beta, vn_bf);
    transpose_kernel<<<dim3(8, 8, NB), 256, 0, stream>>>(vn_bf, vnT_bf);
    kqv_kernel      <<<NB * LL / 64, 256, 0, stream>>>(x, kqvwT, kqvb, qb, kb, vTb);
    attn_kernel     <<<dim3(32, NB), 256, 0, stream>>>(qb, kb, vTb, head_bf);
    mix_kernel      <<<dim3(4, 4, NB), 256, 0, stream>>>(wt_bf, vnT_bf, head_bf, projwT, x, tb, projb, out);
}

// Round 4
// 183.431 us; speedup vs baseline: 2.0256x; 1.0506x over previous
//
#include <hip/hip_runtime.h>
#include <math.h>

#define NB 32
#define LL 512
#define HH 1024
#define H2 512
#define DA 64

typedef unsigned int u32;
typedef unsigned short u16;
typedef __bf16 bf16x8 __attribute__((ext_vector_type(8)));
typedef float f32x4 __attribute__((ext_vector_type(4)));

__device__ __forceinline__ u16 f2bu(float f) {          // fp32 -> bf16 bits, RNE
    u32 u = __builtin_bit_cast(u32, f);
    u = (u + 0x7fff + ((u >> 16) & 1)) >> 16;
    return (u16)u;
}

__device__ __forceinline__ void async_cp16(const void* g, void* l) {
    __builtin_amdgcn_global_load_lds(
        (const __attribute__((address_space(1))) u32*)g,
        (__attribute__((address_space(3))) u32*)l, 16, 0, 0);
}

// ========== fused prep + LayerNorm + transpose ==========
// grid 256 blocks: b = blk>>3, l0 = (blk&7)*64.  Also grid-strides the weight prep.
__global__ __launch_bounds__(256, 2)
void ln_t_kernel(const float* __restrict__ x,
                 const float* __restrict__ gamma, const float* __restrict__ beta,
                 const float* __restrict__ wv, const float* __restrict__ kqvw,
                 const float* __restrict__ projw,
                 u16* __restrict__ vnT, u16* __restrict__ wt,
                 u16* __restrict__ kqvwT, u16* __restrict__ projwT) {
    __shared__ u16 T[64 * 68];
    int blk = blockIdx.x, t = threadIdx.x;
    // ---- prep: 393216 total elements, 1536 per block ----
#pragma unroll
    for (int s = 0; s < 6; ++s) {
        int e = blk * 1536 + s * 256 + t;
        if (e < 262144) {
            int m = e >> 9, l = e & 511;
            wt[e] = f2bu(wv[511 + m - l]);
        } else if (e < 262144 + 98304) {
            int i = e - 262144;
            int n = i >> 9, k = i & 511;
            kqvwT[i] = f2bu(kqvw[(size_t)k * 192 + n]);
        } else {
            int i = e - 360448;
            int c = i >> 6, d = i & 63;
            projwT[i] = f2bu(projw[(size_t)d * 512 + c]);
        }
    }
    // ---- LN stats: thread t -> row r = t>>2, quarter q = t&3 ----
    int b = blk >> 3, l0 = (blk & 7) * 64;
    int r = t >> 2, q = t & 3;
    const float* xr = x + ((size_t)(b * LL + l0 + r)) * HH + H2;
    float s1 = 0.0f, s2 = 0.0f;
#pragma unroll
    for (int i = 0; i < 32; ++i) {
        float4 v = *(const float4*)(xr + q * 128 + i * 4);
        s1 += v.x + v.y + v.z + v.w;
        s2 += v.x * v.x + v.y * v.y + v.z * v.z + v.w * v.w;
    }
    s1 += __shfl_xor(s1, 1); s2 += __shfl_xor(s2, 1);
    s1 += __shfl_xor(s1, 2); s2 += __shfl_xor(s2, 2);
    float mu = s1 * (1.0f / H2);
    float rstd = rsqrtf(s2 * (1.0f / H2) - mu * mu + 1e-5f);
    // ---- normalize + transpose, 8 c-tiles of 64 ----
    for (int ct = 0; ct < 8; ++ct) {
        int cb = (t & 3) * 16;
#pragma unroll
        for (int i = 0; i < 4; ++i) {
            float4 v = *(const float4*)(xr + ct * 64 + cb + i * 4);
            int c = cb + i * 4;
            T[(c + 0) * 68 + r] = f2bu((v.x - mu) * rstd * gamma[ct * 64 + c + 0] + beta[ct * 64 + c + 0]);
            T[(c + 1) * 68 + r] = f2bu((v.y - mu) * rstd * gamma[ct * 64 + c + 1] + beta[ct * 64 + c + 1]);
            T[(c + 2) * 68 + r] = f2bu((v.z - mu) * rstd * gamma[ct * 64 + c + 2] + beta[ct * 64 + c + 2]);
            T[(c + 3) * 68 + r] = f2bu((v.w - mu) * rstd * gamma[ct * 64 + c + 3] + beta[ct * 64 + c + 3]);
        }
        __syncthreads();
        int c = t >> 2, lo = (t & 3) * 16;
        u16* dst = vnT + ((size_t)(b * H2 + ct * 64 + c)) * LL + l0 + lo;
        const u16* src = T + c * 68 + lo;
        ((ushort4*)dst)[0] = ((const ushort4*)src)[0];
        ((ushort4*)dst)[1] = ((const ushort4*)src)[1];
        ((ushort4*)dst)[2] = ((const ushort4*)src)[2];
        ((ushort4*)dst)[3] = ((const ushort4*)src)[3];
        __syncthreads();
    }
}

// ========== kqv MFMA (32-row tiles, BK=64, swizzled B staging) ==========
// out: bf16 q, k row-major [b*L][64]; vT transposed [b*64][512]
__global__ __launch_bounds__(256, 2)
void kqv_kernel(const float* __restrict__ x, const u16* __restrict__ wT,
                const float* __restrict__ bias,
                u16* __restrict__ qb, u16* __restrict__ kb, u16* __restrict__ vT) {
    __shared__ u16 As[32 * 72];                 // padded, ds-written
    __shared__ u16 Bs[192 * 64];                // swizzled, async
    u16* Ts = As;                               // epilogue reuse: [64][36] = 2304 els < 2304 ✓
    int r0 = blockIdx.x * 32;
    int t = threadIdx.x, lane = t & 63, wid = t >> 6;
    int wm = (wid & 1) * 16, wn = (wid >> 1) * 96;
    int l15 = lane & 15, q16 = lane >> 4, q8 = q16 * 8, s7 = l15 & 7;
    f32x4 acc[6] = {};
    for (int k0 = 0; k0 < 512; k0 += 64) {
#pragma unroll
        for (int s = 0; s < 6; ++s) {           // B: 192x64 -> 1536 chunks, swizzled
            int ci = t + s * 256;
            int grow = ci >> 3, gcol = ((ci & 7) ^ (grow & 7)) << 3;
            async_cp16(wT + (size_t)grow * 512 + k0 + gcol, Bs + ci * 8);
        }
#pragma unroll
        for (int s = 0; s < 2; ++s) {           // A: 32x64 fp32->bf16
            int ci = t + s * 256;
            int row = ci >> 4, c4 = (ci & 15) * 4;
            float4 v = *(const float4*)(x + (size_t)(r0 + row) * HH + H2 + k0 + c4);
            ushort4 p;
            p.x = f2bu(v.x); p.y = f2bu(v.y); p.z = f2bu(v.z); p.w = f2bu(v.w);
            *(ushort4*)(As + row * 72 + c4) = p;
        }
        __syncthreads();
#pragma unroll
        for (int kk = 0; kk < 2; ++kk) {
            int j0 = kk * 4 + q16;
            bf16x8 a = *(const bf16x8*)(As + (wm + l15) * 72 + kk * 32 + q8);
#pragma unroll
            for (int j = 0; j < 6; ++j) {
                int n = wn + j * 16 + l15;
                bf16x8 bb = *(const bf16x8*)(Bs + (n * 8 + (j0 ^ (n & 7))) * 8);
                acc[j] = __builtin_amdgcn_mfma_f32_16x16x32_bf16(a, bb, acc[j], 0, 0, 0);
            }
        }
        __syncthreads();
    }
    // epilogue: k -> kb, q -> qb, v -> Ts transpose -> vT
    int bidx = blockIdx.x >> 4, l0loc = (blockIdx.x & 15) * 32;
    int rq = q16 * 4;
#pragma unroll
    for (int r = 0; r < 4; ++r) {
        int mloc = wm + rq + r;
        size_t mg = (size_t)(r0 + mloc);
#pragma unroll
        for (int j = 0; j < 6; ++j) {
            int n = wn + j * 16 + l15;
            u16 hv = f2bu(acc[j][r] + bias[n]);
            if (n < 64)       kb[mg * 64 + n] = hv;
            else if (n < 128) qb[mg * 64 + (n - 64)] = hv;
            else              Ts[(n - 128) * 36 + mloc] = hv;
        }
    }
    __syncthreads();
    int d = t >> 2, lo = (t & 3) * 8;
    u16* dst = vT + ((size_t)(bidx * 64 + d)) * 512 + l0loc + lo;
    const u16* src = Ts + d * 36 + lo;
    ((ushort4*)dst)[0] = ((const ushort4*)src)[0];
    ((ushort4*)dst)[1] = ((const ushort4*)src)[1];
}

// ========== MFMA flash attention, split-K across 4 waves ==========
#define VLD 136
__global__ __launch_bounds__(256, 4)
void attn_kernel(const u16* __restrict__ qb, const u16* __restrict__ kb,
                 const u16* __restrict__ vT, u16* __restrict__ head) {
    __shared__ u16 Ps[4 * 16 * VLD];
    __shared__ float Osh[4][16 * 65];
    __shared__ float Msh[4][16], Lsh[4][16];
    int b = blockIdx.y, q0 = blockIdx.x * 16;
    int t = threadIdx.x, lane = t & 63, w = t >> 6;
    int l15 = lane & 15, q16 = lane >> 4, q8 = q16 * 8;
    int kc = w * 128;
    const u16* qg = qb + (size_t)b * LL * DA;
    const u16* kg = kb + (size_t)b * LL * DA;
    const u16* vg = vT + (size_t)b * DA * LL;

    bf16x8 aq[2];
#pragma unroll
    for (int s = 0; s < 2; ++s)
        aq[s] = *(const bf16x8*)(qg + (size_t)(q0 + l15) * DA + s * 32 + q8);

    f32x4 sc[8] = {};
#pragma unroll
    for (int j = 0; j < 8; ++j) {
#pragma unroll
        for (int s = 0; s < 2; ++s) {
            bf16x8 bk = *(const bf16x8*)(kg + (size_t)(kc + j * 16 + l15) * DA + s * 32 + q8);
            sc[j] = __builtin_amdgcn_mfma_f32_16x16x32_bf16(aq[s], bk, sc[j], 0, 0, 0);
        }
    }
    float mx[4], sm[4];
#pragma unroll
    for (int j = 0; j < 8; ++j)
#pragma unroll
        for (int r = 0; r < 4; ++r) sc[j][r] *= 0.125f;
#pragma unroll
    for (int r = 0; r < 4; ++r) {
        float m0 = sc[0][r];
#pragma unroll
        for (int j = 1; j < 8; ++j) m0 = fmaxf(m0, sc[j][r]);
        m0 = fmaxf(m0, __shfl_xor(m0, 1));
        m0 = fmaxf(m0, __shfl_xor(m0, 2));
        m0 = fmaxf(m0, __shfl_xor(m0, 4));
        m0 = fmaxf(m0, __shfl_xor(m0, 8));
        mx[r] = m0;
    }
#pragma unroll
    for (int j = 0; j < 8; ++j)
#pragma unroll
        for (int r = 0; r < 4; ++r) sc[j][r] = __expf(sc[j][r] - mx[r]);
#pragma unroll
    for (int r = 0; r < 4; ++r) {
        float s0 = sc[0][r];
#pragma unroll
        for (int j = 1; j < 8; ++j) s0 += sc[j][r];
        s0 += __shfl_xor(s0, 1);
        s0 += __shfl_xor(s0, 2);
        s0 += __shfl_xor(s0, 4);
        s0 += __shfl_xor(s0, 8);
        sm[r] = s0;
    }
    u16* Pw = Ps + w * 16 * VLD;
#pragma unroll
    for (int j = 0; j < 8; ++j)
#pragma unroll
        for (int r = 0; r < 4; ++r)
            Pw[(q16 * 4 + r) * VLD + j * 16 + l15] = f2bu(sc[j][r]);
    f32x4 o[4] = {};
#pragma unroll
    for (int kt = 0; kt < 4; ++kt) {
        bf16x8 ap = *(const bf16x8*)(Pw + l15 * VLD + kt * 32 + q8);
#pragma unroll
        for (int j = 0; j < 4; ++j) {
            bf16x8 bv = *(const bf16x8*)(vg + (size_t)(j * 16 + l15) * LL + kc + kt * 32 + q8);
            o[j] = __builtin_amdgcn_mfma_f32_16x16x32_bf16(ap, bv, o[j], 0, 0, 0);
        }
    }
#pragma unroll
    for (int j = 0; j < 4; ++j)
#pragma unroll
        for (int r = 0; r < 4; ++r)
            Osh[w][(q16 * 4 + r) * 65 + j * 16 + l15] = o[j][r];
    if (l15 == 0) {
#pragma unroll
        for (int r = 0; r < 4; ++r) {
            Msh[w][q16 * 4 + r] = mx[r];
            Lsh[w][q16 * 4 + r] = sm[r];
        }
    }
    __syncthreads();
    int qq = t >> 4, dg = (t & 15) * 4;
    float m0 = Msh[0][qq], m1 = Msh[1][qq], m2 = Msh[2][qq], m3 = Msh[3][qq];
    float ms = fmaxf(fmaxf(m0, m1), fmaxf(m2, m3));
    float f0 = __expf(m0 - ms), f1 = __expf(m1 - ms), f2 = __expf(m2 - ms), f3 = __expf(m3 - ms);
    float lst = Lsh[0][qq] * f0 + Lsh[1][qq] * f1 + Lsh[2][qq] * f2 + Lsh[3][qq] * f3;
    float inv = 1.0f / lst;
    ushort4 res;
    u16* rp = (u16*)&res;
#pragma unroll
    for (int i = 0; i < 4; ++i) {
        int idx = qq * 65 + dg + i;
        float a = Osh[0][idx] * f0 + Osh[1][idx] * f1 + Osh[2][idx] * f2 + Osh[3][idx] * f3;
        rp[i] = f2bu(a * inv);
    }
    *(ushort4*)(head + (size_t)(b * LL + q0 + qq) * DA + dg) = res;
}

// ========== fused Toeplitz GEMM + proj + bias + gate (BK=64, swizzled) ==========
__device__ __forceinline__ void mfma_tile64(const u16* As, const u16* Bs,
                                            f32x4 acc[4][4], int wm, int wn,
                                            int l15, int q16) {
    int s7 = l15 & 7;
#pragma unroll
    for (int kk = 0; kk < 2; ++kk) {
        int j0 = kk * 4 + q16;
        bf16x8 a[4], bv[4];
#pragma unroll
        for (int i = 0; i < 4; ++i) {
            int row = wm + i * 16 + l15;
            a[i] = *(const bf16x8*)(As + (row * 8 + (j0 ^ s7)) * 8);
        }
#pragma unroll
        for (int j = 0; j < 4; ++j) {
            int row = wn + j * 16 + l15;
            bv[j] = *(const bf16x8*)(Bs + (row * 8 + (j0 ^ s7)) * 8);
        }
#pragma unroll
        for (int i = 0; i < 4; ++i)
#pragma unroll
            for (int j = 0; j < 4; ++j)
                acc[i][j] = __builtin_amdgcn_mfma_f32_16x16x32_bf16(a[i], bv[j], acc[i][j], 0, 0, 0);
    }
}

__global__ __launch_bounds__(256, 2)
void mix_kernel(const u16* __restrict__ wt,      // [512 m][512 l]
                const u16* __restrict__ vnT,     // [B][512 c][512 l]
                const u16* __restrict__ headb,   // [B][512 m][64 d]
                const u16* __restrict__ projwT,  // [512 c][64 d]
                const float* __restrict__ x,
                const float* __restrict__ tbias,
                const float* __restrict__ projb,
                float* __restrict__ out) {
    __shared__ u16 As[128 * 64];                 // swizzled BK=64 tiles
    __shared__ u16 Bs[128 * 64];
    int b = blockIdx.z, m0 = blockIdx.y * 128, c0 = blockIdx.x * 128;
    int t = threadIdx.x, lane = t & 63, wid = t >> 6;
    int wm = (wid >> 1) * 64, wn = (wid & 1) * 64;
    int l15 = lane & 15, q16 = lane >> 4;
    f32x4 acc[4][4] = {};
    const u16* Ag = wt + (size_t)m0 * 512;
    const u16* Bg = vnT + ((size_t)b * H2 + c0) * 512;
    for (int k0 = 0; k0 < 512; k0 += 64) {       // Toeplitz phase
#pragma unroll
        for (int s = 0; s < 4; ++s) {
            int ci = t + s * 256;
            int grow = ci >> 3, gcol = ((ci & 7) ^ (grow & 7)) << 3;
            async_cp16(Ag + (size_t)grow * 512 + k0 + gcol, As + ci * 8);
            async_cp16(Bg + (size_t)grow * 512 + k0 + gcol, Bs + ci * 8);
        }
        __syncthreads();
        mfma_tile64(As, Bs, acc, wm, wn, l15, q16);
        __syncthreads();
    }
    {                                            // proj phase: single K=64 iteration
        const u16* Hg = headb + ((size_t)b * LL + m0) * DA;
        const u16* Pg = projwT + (size_t)c0 * DA;
#pragma unroll
        for (int s = 0; s < 4; ++s) {
            int ci = t + s * 256;
            int grow = ci >> 3, gcol = ((ci & 7) ^ (grow & 7)) << 3;
            async_cp16(Hg + (size_t)grow * 64 + gcol, As + ci * 8);
            async_cp16(Pg + (size_t)grow * 64 + gcol, Bs + ci * 8);
        }
        __syncthreads();
        mfma_tile64(As, Bs, acc, wm, wn, l15, q16);
        __syncthreads();
    }
    int rq = q16 * 4;
#pragma unroll
    for (int i = 0; i < 4; ++i) {
#pragma unroll
        for (int r = 0; r < 4; ++r) {
            int m = m0 + wm + i * 16 + rq + r;
            float tb = tbias[m];
            const float* xrow = x + ((size_t)b * LL + m) * HH;
            float* orow = out + ((size_t)b * LL + m) * H2;
#pragma unroll
            for (int j = 0; j < 4; ++j) {
                int c = c0 + wn + j * 16 + l15;
                float val = acc[i][j][r] + tb + projb[c];
                orow[c] = xrow[c] * val;
            }
        }
    }
}

extern "C" void kernel_launch(void* const* d_in, const int* in_sizes, int n_in,
                              void* d_out, int out_size, void* d_ws, size_t ws_size,
                              hipStream_t stream) {
    (void)in_sizes; (void)n_in; (void)out_size; (void)ws_size;
    const float* x     = (const float*)d_in[0];
    const float* gamma = (const float*)d_in[1];
    const float* beta  = (const float*)d_in[2];
    const float* wv    = (const float*)d_in[3];
    const float* tb    = (const float*)d_in[4];
    const float* kqvw  = (const float*)d_in[5];
    const float* kqvb  = (const float*)d_in[6];
    const float* projw = (const float*)d_in[7];
    const float* projb = (const float*)d_in[8];
    float* out = (float*)d_out;

    u16* vnT_bf  = (u16*)d_ws;                          // 16 MB
    u16* qb      = vnT_bf + (size_t)NB * LL * H2;       // 2 MB
    u16* kb      = qb + (size_t)NB * LL * DA;           // 2 MB
    u16* vTb     = kb + (size_t)NB * LL * DA;           // 2 MB
    u16* head_bf = vTb + (size_t)NB * LL * DA;          // 2 MB
    u16* wt_bf   = head_bf + (size_t)NB * LL * DA;      // 512 KB
    u16* kqvwT   = wt_bf + 512 * 512;                   // 192 KB
    u16* projwT  = kqvwT + 192 * 512;                   // 64 KB

    ln_t_kernel<<<256, 256, 0, stream>>>(x, gamma, beta, wv, kqvw, projw,
                                         vnT_bf, wt_bf, kqvwT, projwT);
    kqv_kernel <<<NB * LL / 32, 256, 0, stream>>>(x, kqvwT, kqvb, qb, kb, vTb);
    attn_kernel<<<dim3(32, NB), 256, 0, stream>>>(qb, kb, vTb, head_bf);
    mix_kernel <<<dim3(4, 4, NB), 256, 0, stream>>>(wt_bf, vnT_bf, head_bf, projwT,
                                                    x, tb, projb, out);
}

// Round 5
// 181.416 us; speedup vs baseline: 2.0481x; 1.0111x over previous
//
#include <hip/hip_runtime.h>
#include <math.h>

#define NB 32
#define LL 512
#define HH 1024
#define H2 512
#define DA 64

typedef unsigned int u32;
typedef unsigned short u16;
typedef __bf16 bf16x8 __attribute__((ext_vector_type(8)));
typedef float f32x4 __attribute__((ext_vector_type(4)));

__device__ __forceinline__ u16 f2bu(float f) {          // fp32 -> bf16 bits, RNE
    u32 u = __builtin_bit_cast(u32, f);
    u = (u + 0x7fff + ((u >> 16) & 1)) >> 16;
    return (u16)u;
}

__device__ __forceinline__ void async_cp16(const void* g, void* l) {
    __builtin_amdgcn_global_load_lds(
        (const __attribute__((address_space(1))) u32*)g,
        (__attribute__((address_space(3))) u32*)l, 16, 0, 0);
}

// ========== prep: bf16 weight materialization (tiny, hidden latency) ==========
__global__ void prep_kernel(const float* __restrict__ wv,
                            const float* __restrict__ kqvw,
                            const float* __restrict__ projw,
                            u16* __restrict__ wt, u16* __restrict__ kqvwT,
                            u16* __restrict__ projwT) {
    int e = blockIdx.x * 256 + threadIdx.x;
    if (e < 262144) {
        int m = e >> 9, l = e & 511;
        wt[e] = f2bu(wv[511 + m - l]);
    } else if (e < 262144 + 98304) {
        int i = e - 262144;
        int n = i >> 9, k = i & 511;
        kqvwT[i] = f2bu(kqvw[(size_t)k * 192 + n]);
    } else {
        int i = e - 360448;
        int c = i >> 6, d = i & 63;
        projwT[i] = f2bu(projw[(size_t)d * 512 + c]);
    }
}

// ========== front: LN stats + normalize/transpose + kqv GEMM (64-row tiles) ==========
// grid 256: b = blk>>3, l0 = (blk&7)*64.  x v-half read cold once; re-reads are L1/L2-hot.
__global__ __launch_bounds__(256, 2)
void front_kernel(const float* __restrict__ x,
                  const float* __restrict__ gamma, const float* __restrict__ beta,
                  const u16* __restrict__ kqvwT, const float* __restrict__ kqvb,
                  u16* __restrict__ vnT,
                  u16* __restrict__ qb, u16* __restrict__ kb, u16* __restrict__ vT) {
    __shared__ u16 smem[64 * 72 + 192 * 64];    // As | Bs ; T/Ts alias Bs
    u16* As = smem;
    u16* Bs = smem + 64 * 72;
    u16* T  = Bs;                               // 64x68 transpose buffer (8704 <= 12288)
    int blk = blockIdx.x, t = threadIdx.x;
    int b = blk >> 3, l0 = (blk & 7) * 64;
    int lane = t & 63, wid = t >> 6;
    int l15 = lane & 15, q16 = lane >> 4, q8 = q16 * 8;

    // ---- phase 1: LN stats (thread t -> row r=t>>2, quarter q=t&3) ----
    int r = t >> 2, q = t & 3;
    const float* xr = x + ((size_t)(b * LL + l0 + r)) * HH + H2;
    float s1 = 0.0f, s2 = 0.0f;
#pragma unroll
    for (int i = 0; i < 32; ++i) {
        float4 v = *(const float4*)(xr + q * 128 + i * 4);
        s1 += v.x + v.y + v.z + v.w;
        s2 += v.x * v.x + v.y * v.y + v.z * v.z + v.w * v.w;
    }
    s1 += __shfl_xor(s1, 1); s2 += __shfl_xor(s2, 1);
    s1 += __shfl_xor(s1, 2); s2 += __shfl_xor(s2, 2);
    float mu = s1 * (1.0f / H2);
    float rstd = rsqrtf(s2 * (1.0f / H2) - mu * mu + 1e-5f);

    // ---- phase 2: normalize + transpose -> vnT (re-reads x, L1/L2-hot) ----
    for (int ct = 0; ct < 8; ++ct) {
        int cb = (t & 3) * 16;
#pragma unroll
        for (int i = 0; i < 4; ++i) {
            float4 v = *(const float4*)(xr + ct * 64 + cb + i * 4);
            int c = cb + i * 4;
            T[(c + 0) * 68 + r] = f2bu((v.x - mu) * rstd * gamma[ct * 64 + c + 0] + beta[ct * 64 + c + 0]);
            T[(c + 1) * 68 + r] = f2bu((v.y - mu) * rstd * gamma[ct * 64 + c + 1] + beta[ct * 64 + c + 1]);
            T[(c + 2) * 68 + r] = f2bu((v.z - mu) * rstd * gamma[ct * 64 + c + 2] + beta[ct * 64 + c + 2]);
            T[(c + 3) * 68 + r] = f2bu((v.w - mu) * rstd * gamma[ct * 64 + c + 3] + beta[ct * 64 + c + 3]);
        }
        __syncthreads();
        int c = t >> 2, lo = (t & 3) * 16;
        u16* dst = vnT + ((size_t)(b * H2 + ct * 64 + c)) * LL + l0 + lo;
        const u16* src = T + c * 68 + lo;
        ((ushort4*)dst)[0] = ((const ushort4*)src)[0];
        ((ushort4*)dst)[1] = ((const ushort4*)src)[1];
        ((ushort4*)dst)[2] = ((const ushort4*)src)[2];
        ((ushort4*)dst)[3] = ((const ushort4*)src)[3];
        __syncthreads();
    }

    // ---- phase 3: kqv GEMM, M=64, N=192, BK=64 (A from hot x, B async swizzled) ----
    int wm = (wid & 1) * 32, wn = (wid >> 1) * 96;
    f32x4 acc[2][6] = {};
    for (int k0 = 0; k0 < 512; k0 += 64) {
#pragma unroll
        for (int s = 0; s < 6; ++s) {           // B: 192x64 -> 1536 16B chunks, swizzled
            int ci = t + s * 256;
            int grow = ci >> 3, gcol = ((ci & 7) ^ (grow & 7)) << 3;
            async_cp16(kqvwT + (size_t)grow * 512 + k0 + gcol, Bs + ci * 8);
        }
#pragma unroll
        for (int s = 0; s < 4; ++s) {           // A: 64x64 fp32->bf16
            int ci = t + s * 256;
            int row = ci >> 4, c4 = (ci & 15) * 4;
            float4 v = *(const float4*)(x + (size_t)(b * LL + l0 + row) * HH + H2 + k0 + c4);
            ushort4 p;
            p.x = f2bu(v.x); p.y = f2bu(v.y); p.z = f2bu(v.z); p.w = f2bu(v.w);
            *(ushort4*)(As + row * 72 + c4) = p;
        }
        __syncthreads();
#pragma unroll
        for (int kk = 0; kk < 2; ++kk) {
            int j0 = kk * 4 + q16;
            bf16x8 a[2];
#pragma unroll
            for (int i = 0; i < 2; ++i)
                a[i] = *(const bf16x8*)(As + (wm + i * 16 + l15) * 72 + kk * 32 + q8);
#pragma unroll
            for (int j = 0; j < 6; ++j) {
                int n = wn + j * 16 + l15;
                bf16x8 bb = *(const bf16x8*)(Bs + (n * 8 + (j0 ^ (n & 7))) * 8);
#pragma unroll
                for (int i = 0; i < 2; ++i)
                    acc[i][j] = __builtin_amdgcn_mfma_f32_16x16x32_bf16(a[i], bb, acc[i][j], 0, 0, 0);
            }
        }
        __syncthreads();
    }
    // ---- phase 4: epilogue k -> kb, q -> qb, v -> Ts transpose -> vT ----
    u16* Ts = Bs;                               // 64x68
    int rq = q16 * 4;
#pragma unroll
    for (int i = 0; i < 2; ++i)
#pragma unroll
        for (int rr = 0; rr < 4; ++rr) {
            int mloc = wm + i * 16 + rq + rr;
            size_t mg = (size_t)(b * LL + l0 + mloc);
#pragma unroll
            for (int j = 0; j < 6; ++j) {
                int n = wn + j * 16 + l15;
                u16 hv = f2bu(acc[i][j][rr] + kqvb[n]);
                if (n < 64)       kb[mg * 64 + n] = hv;
                else if (n < 128) qb[mg * 64 + (n - 64)] = hv;
                else              Ts[(n - 128) * 68 + mloc] = hv;
            }
        }
    __syncthreads();
    int d = t >> 2, mo = (t & 3) * 16;
    u16* dst = vT + ((size_t)(b * 64 + d)) * 512 + l0 + mo;
    const u16* srcl = Ts + d * 68 + mo;
#pragma unroll
    for (int c = 0; c < 4; ++c)
        ((ushort4*)dst)[c] = ((const ushort4*)srcl)[c];
}

// ========== MFMA flash attention, split-K across 4 waves ==========
#define VLD 136
__global__ __launch_bounds__(256, 4)
void attn_kernel(const u16* __restrict__ qb, const u16* __restrict__ kb,
                 const u16* __restrict__ vT, u16* __restrict__ head) {
    __shared__ u16 Ps[4 * 16 * VLD];
    __shared__ float Osh[4][16 * 65];
    __shared__ float Msh[4][16], Lsh[4][16];
    int b = blockIdx.y, q0 = blockIdx.x * 16;
    int t = threadIdx.x, lane = t & 63, w = t >> 6;
    int l15 = lane & 15, q16 = lane >> 4, q8 = q16 * 8;
    int kc = w * 128;
    const u16* qg = qb + (size_t)b * LL * DA;
    const u16* kg = kb + (size_t)b * LL * DA;
    const u16* vg = vT + (size_t)b * DA * LL;

    bf16x8 aq[2];
#pragma unroll
    for (int s = 0; s < 2; ++s)
        aq[s] = *(const bf16x8*)(qg + (size_t)(q0 + l15) * DA + s * 32 + q8);

    f32x4 sc[8] = {};
#pragma unroll
    for (int j = 0; j < 8; ++j) {
#pragma unroll
        for (int s = 0; s < 2; ++s) {
            bf16x8 bk = *(const bf16x8*)(kg + (size_t)(kc + j * 16 + l15) * DA + s * 32 + q8);
            sc[j] = __builtin_amdgcn_mfma_f32_16x16x32_bf16(aq[s], bk, sc[j], 0, 0, 0);
        }
    }
    float mx[4], sm[4];
#pragma unroll
    for (int j = 0; j < 8; ++j)
#pragma unroll
        for (int rr = 0; rr < 4; ++rr) sc[j][rr] *= 0.125f;
#pragma unroll
    for (int rr = 0; rr < 4; ++rr) {
        float m0 = sc[0][rr];
#pragma unroll
        for (int j = 1; j < 8; ++j) m0 = fmaxf(m0, sc[j][rr]);
        m0 = fmaxf(m0, __shfl_xor(m0, 1));
        m0 = fmaxf(m0, __shfl_xor(m0, 2));
        m0 = fmaxf(m0, __shfl_xor(m0, 4));
        m0 = fmaxf(m0, __shfl_xor(m0, 8));
        mx[rr] = m0;
    }
#pragma unroll
    for (int j = 0; j < 8; ++j)
#pragma unroll
        for (int rr = 0; rr < 4; ++rr) sc[j][rr] = __expf(sc[j][rr] - mx[rr]);
#pragma unroll
    for (int rr = 0; rr < 4; ++rr) {
        float s0 = sc[0][rr];
#pragma unroll
        for (int j = 1; j < 8; ++j) s0 += sc[j][rr];
        s0 += __shfl_xor(s0, 1);
        s0 += __shfl_xor(s0, 2);
        s0 += __shfl_xor(s0, 4);
        s0 += __shfl_xor(s0, 8);
        sm[rr] = s0;
    }
    u16* Pw = Ps + w * 16 * VLD;
#pragma unroll
    for (int j = 0; j < 8; ++j)
#pragma unroll
        for (int rr = 0; rr < 4; ++rr)
            Pw[(q16 * 4 + rr) * VLD + j * 16 + l15] = f2bu(sc[j][rr]);
    f32x4 o[4] = {};
#pragma unroll
    for (int kt = 0; kt < 4; ++kt) {
        bf16x8 ap = *(const bf16x8*)(Pw + l15 * VLD + kt * 32 + q8);
#pragma unroll
        for (int j = 0; j < 4; ++j) {
            bf16x8 bv = *(const bf16x8*)(vg + (size_t)(j * 16 + l15) * LL + kc + kt * 32 + q8);
            o[j] = __builtin_amdgcn_mfma_f32_16x16x32_bf16(ap, bv, o[j], 0, 0, 0);
        }
    }
#pragma unroll
    for (int j = 0; j < 4; ++j)
#pragma unroll
        for (int rr = 0; rr < 4; ++rr)
            Osh[w][(q16 * 4 + rr) * 65 + j * 16 + l15] = o[j][rr];
    if (l15 == 0) {
#pragma unroll
        for (int rr = 0; rr < 4; ++rr) {
            Msh[w][q16 * 4 + rr] = mx[rr];
            Lsh[w][q16 * 4 + rr] = sm[rr];
        }
    }
    __syncthreads();
    int qq = t >> 4, dg = (t & 15) * 4;
    float m0 = Msh[0][qq], m1 = Msh[1][qq], m2 = Msh[2][qq], m3 = Msh[3][qq];
    float ms = fmaxf(fmaxf(m0, m1), fmaxf(m2, m3));
    float f0 = __expf(m0 - ms), f1 = __expf(m1 - ms), f2 = __expf(m2 - ms), f3 = __expf(m3 - ms);
    float lst = Lsh[0][qq] * f0 + Lsh[1][qq] * f1 + Lsh[2][qq] * f2 + Lsh[3][qq] * f3;
    float inv = 1.0f / lst;
    ushort4 res;
    u16* rp = (u16*)&res;
#pragma unroll
    for (int i = 0; i < 4; ++i) {
        int idx = qq * 65 + dg + i;
        float a = Osh[0][idx] * f0 + Osh[1][idx] * f1 + Osh[2][idx] * f2 + Osh[3][idx] * f3;
        rp[i] = f2bu(a * inv);
    }
    *(ushort4*)(head + (size_t)(b * LL + q0 + qq) * DA + dg) = res;
}

// ========== fused Toeplitz GEMM + proj + bias + gate (BK=64, XCD-swizzled grid) ==========
__device__ __forceinline__ void mfma_tile64(const u16* As, const u16* Bs,
                                            f32x4 acc[4][4], int wm, int wn,
                                            int l15, int q16) {
    int s7 = l15 & 7;
#pragma unroll
    for (int kk = 0; kk < 2; ++kk) {
        int j0 = kk * 4 + q16;
        bf16x8 a[4], bv[4];
#pragma unroll
        for (int i = 0; i < 4; ++i) {
            int row = wm + i * 16 + l15;
            a[i] = *(const bf16x8*)(As + (row * 8 + (j0 ^ s7)) * 8);
        }
#pragma unroll
        for (int j = 0; j < 4; ++j) {
            int row = wn + j * 16 + l15;
            bv[j] = *(const bf16x8*)(Bs + (row * 8 + (j0 ^ s7)) * 8);
        }
#pragma unroll
        for (int i = 0; i < 4; ++i)
#pragma unroll
            for (int j = 0; j < 4; ++j)
                acc[i][j] = __builtin_amdgcn_mfma_f32_16x16x32_bf16(a[i], bv[j], acc[i][j], 0, 0, 0);
    }
}

__global__ __launch_bounds__(256, 2)
void mix_kernel(const u16* __restrict__ wt,      // [512 m][512 l]
                const u16* __restrict__ vnT,     // [B][512 c][512 l]
                const u16* __restrict__ headb,   // [B][512 m][64 d]
                const u16* __restrict__ projwT,  // [512 c][64 d]
                const float* __restrict__ x,
                const float* __restrict__ tbias,
                const float* __restrict__ projb,
                float* __restrict__ out) {
    __shared__ u16 As[128 * 64];
    __shared__ u16 Bs[128 * 64];
    // XCD-aware decode: the 4 m-blocks sharing (b,c0) get equal lid%8 -> same XCD
    int lid = blockIdx.x;
    int p8 = lid & 7, rest = lid >> 3;
    int mi = rest & 3, pair = (rest >> 2) * 8 + p8;   // pair in [0,128)
    int b = pair >> 2, m0 = mi * 128, c0 = (pair & 3) * 128;
    int t = threadIdx.x, lane = t & 63, wid = t >> 6;
    int wm = (wid >> 1) * 64, wn = (wid & 1) * 64;
    int l15 = lane & 15, q16 = lane >> 4;
    f32x4 acc[4][4] = {};
    const u16* Ag = wt + (size_t)m0 * 512;
    const u16* Bg = vnT + ((size_t)b * H2 + c0) * 512;
    for (int k0 = 0; k0 < 512; k0 += 64) {       // Toeplitz phase
#pragma unroll
        for (int s = 0; s < 4; ++s) {
            int ci = t + s * 256;
            int grow = ci >> 3, gcol = ((ci & 7) ^ (grow & 7)) << 3;
            async_cp16(Ag + (size_t)grow * 512 + k0 + gcol, As + ci * 8);
            async_cp16(Bg + (size_t)grow * 512 + k0 + gcol, Bs + ci * 8);
        }
        __syncthreads();
        mfma_tile64(As, Bs, acc, wm, wn, l15, q16);
        __syncthreads();
    }
    {                                            // proj phase: single K=64 iteration
        const u16* Hg = headb + ((size_t)b * LL + m0) * DA;
        const u16* Pg = projwT + (size_t)c0 * DA;
#pragma unroll
        for (int s = 0; s < 4; ++s) {
            int ci = t + s * 256;
            int grow = ci >> 3, gcol = ((ci & 7) ^ (grow & 7)) << 3;
            async_cp16(Hg + (size_t)grow * 64 + gcol, As + ci * 8);
            async_cp16(Pg + (size_t)grow * 64 + gcol, Bs + ci * 8);
        }
        __syncthreads();
        mfma_tile64(As, Bs, acc, wm, wn, l15, q16);
        __syncthreads();
    }
    int rq = q16 * 4;
#pragma unroll
    for (int i = 0; i < 4; ++i) {
#pragma unroll
        for (int rr = 0; rr < 4; ++rr) {
            int m = m0 + wm + i * 16 + rq + rr;
            float tb = tbias[m];
            const float* xrow = x + ((size_t)b * LL + m) * HH;
            float* orow = out + ((size_t)b * LL + m) * H2;
#pragma unroll
            for (int j = 0; j < 4; ++j) {
                int c = c0 + wn + j * 16 + l15;
                float val = acc[i][j][rr] + tb + projb[c];
                orow[c] = xrow[c] * val;
            }
        }
    }
}

extern "C" void kernel_launch(void* const* d_in, const int* in_sizes, int n_in,
                              void* d_out, int out_size, void* d_ws, size_t ws_size,
                              hipStream_t stream) {
    (void)in_sizes; (void)n_in; (void)out_size; (void)ws_size;
    const float* x     = (const float*)d_in[0];
    const float* gamma = (const float*)d_in[1];
    const float* beta  = (const float*)d_in[2];
    const float* wv    = (const float*)d_in[3];
    const float* tb    = (const float*)d_in[4];
    const float* kqvw  = (const float*)d_in[5];
    const float* kqvb  = (const float*)d_in[6];
    const float* projw = (const float*)d_in[7];
    const float* projb = (const float*)d_in[8];
    float* out = (float*)d_out;

    u16* vnT_bf  = (u16*)d_ws;                          // 16 MB
    u16* qb      = vnT_bf + (size_t)NB * LL * H2;       // 2 MB
    u16* kb      = qb + (size_t)NB * LL * DA;           // 2 MB
    u16* vTb     = kb + (size_t)NB * LL * DA;           // 2 MB
    u16* head_bf = vTb + (size_t)NB * LL * DA;          // 2 MB
    u16* wt_bf   = head_bf + (size_t)NB * LL * DA;      // 512 KB
    u16* kqvwT   = wt_bf + 512 * 512;                   // 192 KB
    u16* projwT  = kqvwT + 192 * 512;                   // 64 KB

    prep_kernel <<<1536, 256, 0, stream>>>(wv, kqvw, projw, wt_bf, kqvwT, projwT);
    front_kernel<<<256, 256, 0, stream>>>(x, gamma, beta, kqvwT, kqvb,
                                          vnT_bf, qb, kb, vTb);
    attn_kernel <<<dim3(32, NB), 256, 0, stream>>>(qb, kb, vTb, head_bf);
    mix_kernel  <<<512, 256, 0, stream>>>(wt_bf, vnT_bf, head_bf, projwT,
                                          x, tb, projb, out);
}

// Round 6
// 176.323 us; speedup vs baseline: 2.1072x; 1.0289x over previous
//
#include <hip/hip_runtime.h>
#include <math.h>

#define NB 32
#define LL 512
#define HH 1024
#define H2 512
#define DA 64

typedef unsigned int u32;
typedef unsigned short u16;
typedef __bf16 bf16x8 __attribute__((ext_vector_type(8)));
typedef float f32x4 __attribute__((ext_vector_type(4)));

__device__ __forceinline__ u16 f2bu(float f) {          // fp32 -> bf16 bits, RNE
    u32 u = __builtin_bit_cast(u32, f);
    u = (u + 0x7fff + ((u >> 16) & 1)) >> 16;
    return (u16)u;
}

__device__ __forceinline__ void async_cp16(const void* g, void* l) {
    __builtin_amdgcn_global_load_lds(
        (const __attribute__((address_space(1))) u32*)g,
        (__attribute__((address_space(3))) u32*)l, 16, 0, 0);
}

// ========== prep: bf16 weight materialization (tiny, serial but short) ==========
__global__ void prep_kernel(const float* __restrict__ wv,
                            const float* __restrict__ kqvw,
                            const float* __restrict__ projw,
                            u16* __restrict__ wt, u16* __restrict__ kqvwT,
                            u16* __restrict__ projwT) {
    int e = blockIdx.x * 256 + threadIdx.x;
    if (e < 262144) {
        int m = e >> 9, l = e & 511;
        wt[e] = f2bu(wv[511 + m - l]);
    } else if (e < 262144 + 98304) {
        int i = e - 262144;
        int n = i >> 9, k = i & 511;
        kqvwT[i] = f2bu(kqvw[(size_t)k * 192 + n]);
    } else {
        int i = e - 360448;
        int c = i >> 6, d = i & 63;
        projwT[i] = f2bu(projw[(size_t)d * 512 + c]);
    }
}

// ========== front: LN + transpose + kqv GEMM, 32-row tiles, 512 blocks (2/CU) ==========
__global__ __launch_bounds__(256, 2)
void front_kernel(const float* __restrict__ x,
                  const float* __restrict__ gamma, const float* __restrict__ beta,
                  const u16* __restrict__ kqvwT, const float* __restrict__ kqvb,
                  u16* __restrict__ vnT,
                  u16* __restrict__ qb, u16* __restrict__ kb, u16* __restrict__ vT) {
    __shared__ u16 As[32 * 72];                 // 2304  (aliased as Ts[64][36] in epilogue)
    __shared__ u16 Bs[192 * 64];                // 12288 (async, swizzled)
    __shared__ u16 T[64 * 36];                  // 2304  (transpose staging)
    int blk = blockIdx.x, t = threadIdx.x;
    int b = blk >> 4, l0 = (blk & 15) * 32;
    int lane = t & 63, wid = t >> 6;
    int l15 = lane & 15, q16 = lane >> 4, q8 = q16 * 8;

    // ---- phase 0: prefetch Bs(k0=0) -- DMA overlaps the LN phase ----
#pragma unroll
    for (int s = 0; s < 6; ++s) {
        int ci = t + s * 256;
        int grow = ci >> 3, gcol = ((ci & 7) ^ (grow & 7)) << 3;
        async_cp16(kqvwT + (size_t)grow * 512 + gcol, Bs + ci * 8);
    }

    // ---- phase 1: LN stats (8 threads/row, row r = t>>3, seg q = t&7) ----
    int r = t >> 3, q = t & 7;
    const float* xr = x + ((size_t)(b * LL + l0 + r)) * HH + H2;
    float s1 = 0.0f, s2 = 0.0f;
#pragma unroll
    for (int i = 0; i < 16; ++i) {
        float4 v = *(const float4*)(xr + q * 64 + i * 4);
        s1 += v.x + v.y + v.z + v.w;
        s2 += v.x * v.x + v.y * v.y + v.z * v.z + v.w * v.w;
    }
    s1 += __shfl_xor(s1, 1); s2 += __shfl_xor(s2, 1);
    s1 += __shfl_xor(s1, 2); s2 += __shfl_xor(s2, 2);
    s1 += __shfl_xor(s1, 4); s2 += __shfl_xor(s2, 4);
    float mu = s1 * (1.0f / H2);
    float rstd = rsqrtf(s2 * (1.0f / H2) - mu * mu + 1e-5f);

    // ---- phase 2: normalize + transpose -> vnT (x re-reads are L1/L2-hot) ----
    int c8 = (t & 7) * 8;                       // this thread's 8 columns within a 64-c tile
    for (int ct = 0; ct < 8; ++ct) {
        float4 v0 = *(const float4*)(xr + ct * 64 + c8);
        float4 v1 = *(const float4*)(xr + ct * 64 + c8 + 4);
        const float* g = gamma + ct * 64 + c8;
        const float* be = beta + ct * 64 + c8;
        T[(c8 + 0) * 36 + r] = f2bu((v0.x - mu) * rstd * g[0] + be[0]);
        T[(c8 + 1) * 36 + r] = f2bu((v0.y - mu) * rstd * g[1] + be[1]);
        T[(c8 + 2) * 36 + r] = f2bu((v0.z - mu) * rstd * g[2] + be[2]);
        T[(c8 + 3) * 36 + r] = f2bu((v0.w - mu) * rstd * g[3] + be[3]);
        T[(c8 + 4) * 36 + r] = f2bu((v1.x - mu) * rstd * g[4] + be[4]);
        T[(c8 + 5) * 36 + r] = f2bu((v1.y - mu) * rstd * g[5] + be[5]);
        T[(c8 + 6) * 36 + r] = f2bu((v1.z - mu) * rstd * g[6] + be[6]);
        T[(c8 + 7) * 36 + r] = f2bu((v1.w - mu) * rstd * g[7] + be[7]);
        __syncthreads();
        int c = t >> 2, lo = (t & 3) * 8;
        u16* dst = vnT + ((size_t)(b * H2 + ct * 64 + c)) * LL + l0 + lo;
        const u16* src = T + c * 36 + lo;
        ((ushort4*)dst)[0] = ((const ushort4*)src)[0];
        ((ushort4*)dst)[1] = ((const ushort4*)src)[1];
        __syncthreads();
    }

    // ---- phase 3: kqv GEMM, M=32, N=192, BK=64 (R4-proven body) ----
    int wm = (wid & 1) * 16, wn = (wid >> 1) * 96;
    f32x4 acc[6] = {};
    for (int k0 = 0; k0 < 512; k0 += 64) {
        if (k0 > 0) {
#pragma unroll
            for (int s = 0; s < 6; ++s) {       // B: 192x64 -> 1536 chunks, swizzled
                int ci = t + s * 256;
                int grow = ci >> 3, gcol = ((ci & 7) ^ (grow & 7)) << 3;
                async_cp16(kqvwT + (size_t)grow * 512 + k0 + gcol, Bs + ci * 8);
            }
        }
#pragma unroll
        for (int s = 0; s < 2; ++s) {           // A: 32x64 fp32->bf16 (L2-hot x)
            int ci = t + s * 256;
            int row = ci >> 4, c4 = (ci & 15) * 4;
            float4 v = *(const float4*)(x + (size_t)(b * LL + l0 + row) * HH + H2 + k0 + c4);
            ushort4 p;
            p.x = f2bu(v.x); p.y = f2bu(v.y); p.z = f2bu(v.z); p.w = f2bu(v.w);
            *(ushort4*)(As + row * 72 + c4) = p;
        }
        __syncthreads();
#pragma unroll
        for (int kk = 0; kk < 2; ++kk) {
            int j0 = kk * 4 + q16;
            bf16x8 a = *(const bf16x8*)(As + (wm + l15) * 72 + kk * 32 + q8);
#pragma unroll
            for (int j = 0; j < 6; ++j) {
                int n = wn + j * 16 + l15;
                bf16x8 bb = *(const bf16x8*)(Bs + (n * 8 + (j0 ^ (n & 7))) * 8);
                acc[j] = __builtin_amdgcn_mfma_f32_16x16x32_bf16(a, bb, acc[j], 0, 0, 0);
            }
        }
        __syncthreads();
    }
    // ---- phase 4: epilogue k -> kb, q -> qb, v -> Ts transpose -> vT ----
    u16* Ts = As;                               // [64][36] = 2304 els, exact fit
    int rq = q16 * 4;
#pragma unroll
    for (int rr = 0; rr < 4; ++rr) {
        int mloc = wm + rq + rr;
        size_t mg = (size_t)(b * LL + l0 + mloc);
#pragma unroll
        for (int j = 0; j < 6; ++j) {
            int n = wn + j * 16 + l15;
            u16 hv = f2bu(acc[j][rr] + kqvb[n]);
            if (n < 64)       kb[mg * 64 + n] = hv;
            else if (n < 128) qb[mg * 64 + (n - 64)] = hv;
            else              Ts[(n - 128) * 36 + mloc] = hv;
        }
    }
    __syncthreads();
    int d = t >> 2, lo2 = (t & 3) * 8;
    u16* dst = vT + ((size_t)(b * 64 + d)) * 512 + l0 + lo2;
    const u16* src = Ts + d * 36 + lo2;
    ((ushort4*)dst)[0] = ((const ushort4*)src)[0];
    ((ushort4*)dst)[1] = ((const ushort4*)src)[1];
}

// ========== MFMA flash attention, split-K across 4 waves ==========
#define VLD 136
__global__ __launch_bounds__(256, 4)
void attn_kernel(const u16* __restrict__ qb, const u16* __restrict__ kb,
                 const u16* __restrict__ vT, u16* __restrict__ head) {
    __shared__ u16 Ps[4 * 16 * VLD];
    __shared__ float Osh[4][16 * 65];
    __shared__ float Msh[4][16], Lsh[4][16];
    int b = blockIdx.y, q0 = blockIdx.x * 16;
    int t = threadIdx.x, lane = t & 63, w = t >> 6;
    int l15 = lane & 15, q16 = lane >> 4, q8 = q16 * 8;
    int kc = w * 128;
    const u16* qg = qb + (size_t)b * LL * DA;
    const u16* kg = kb + (size_t)b * LL * DA;
    const u16* vg = vT + (size_t)b * DA * LL;

    bf16x8 aq[2];
#pragma unroll
    for (int s = 0; s < 2; ++s)
        aq[s] = *(const bf16x8*)(qg + (size_t)(q0 + l15) * DA + s * 32 + q8);

    f32x4 sc[8] = {};
#pragma unroll
    for (int j = 0; j < 8; ++j) {
#pragma unroll
        for (int s = 0; s < 2; ++s) {
            bf16x8 bk = *(const bf16x8*)(kg + (size_t)(kc + j * 16 + l15) * DA + s * 32 + q8);
            sc[j] = __builtin_amdgcn_mfma_f32_16x16x32_bf16(aq[s], bk, sc[j], 0, 0, 0);
        }
    }
    float mx[4], sm[4];
#pragma unroll
    for (int j = 0; j < 8; ++j)
#pragma unroll
        for (int rr = 0; rr < 4; ++rr) sc[j][rr] *= 0.125f;
#pragma unroll
    for (int rr = 0; rr < 4; ++rr) {
        float m0 = sc[0][rr];
#pragma unroll
        for (int j = 1; j < 8; ++j) m0 = fmaxf(m0, sc[j][rr]);
        m0 = fmaxf(m0, __shfl_xor(m0, 1));
        m0 = fmaxf(m0, __shfl_xor(m0, 2));
        m0 = fmaxf(m0, __shfl_xor(m0, 4));
        m0 = fmaxf(m0, __shfl_xor(m0, 8));
        mx[rr] = m0;
    }
#pragma unroll
    for (int j = 0; j < 8; ++j)
#pragma unroll
        for (int rr = 0; rr < 4; ++rr) sc[j][rr] = __expf(sc[j][rr] - mx[rr]);
#pragma unroll
    for (int rr = 0; rr < 4; ++rr) {
        float s0 = sc[0][rr];
#pragma unroll
        for (int j = 1; j < 8; ++j) s0 += sc[j][rr];
        s0 += __shfl_xor(s0, 1);
        s0 += __shfl_xor(s0, 2);
        s0 += __shfl_xor(s0, 4);
        s0 += __shfl_xor(s0, 8);
        sm[rr] = s0;
    }
    u16* Pw = Ps + w * 16 * VLD;
#pragma unroll
    for (int j = 0; j < 8; ++j)
#pragma unroll
        for (int rr = 0; rr < 4; ++rr)
            Pw[(q16 * 4 + rr) * VLD + j * 16 + l15] = f2bu(sc[j][rr]);
    f32x4 o[4] = {};
#pragma unroll
    for (int kt = 0; kt < 4; ++kt) {
        bf16x8 ap = *(const bf16x8*)(Pw + l15 * VLD + kt * 32 + q8);
#pragma unroll
        for (int j = 0; j < 4; ++j) {
            bf16x8 bv = *(const bf16x8*)(vg + (size_t)(j * 16 + l15) * LL + kc + kt * 32 + q8);
            o[j] = __builtin_amdgcn_mfma_f32_16x16x32_bf16(ap, bv, o[j], 0, 0, 0);
        }
    }
#pragma unroll
    for (int j = 0; j < 4; ++j)
#pragma unroll
        for (int rr = 0; rr < 4; ++rr)
            Osh[w][(q16 * 4 + rr) * 65 + j * 16 + l15] = o[j][rr];
    if (l15 == 0) {
#pragma unroll
        for (int rr = 0; rr < 4; ++rr) {
            Msh[w][q16 * 4 + rr] = mx[rr];
            Lsh[w][q16 * 4 + rr] = sm[rr];
        }
    }
    __syncthreads();
    int qq = t >> 4, dg = (t & 15) * 4;
    float m0 = Msh[0][qq], m1 = Msh[1][qq], m2 = Msh[2][qq], m3 = Msh[3][qq];
    float ms = fmaxf(fmaxf(m0, m1), fmaxf(m2, m3));
    float f0 = __expf(m0 - ms), f1 = __expf(m1 - ms), f2 = __expf(m2 - ms), f3 = __expf(m3 - ms);
    float lst = Lsh[0][qq] * f0 + Lsh[1][qq] * f1 + Lsh[2][qq] * f2 + Lsh[3][qq] * f3;
    float inv = 1.0f / lst;
    ushort4 res;
    u16* rp = (u16*)&res;
#pragma unroll
    for (int i = 0; i < 4; ++i) {
        int idx = qq * 65 + dg + i;
        float a = Osh[0][idx] * f0 + Osh[1][idx] * f1 + Osh[2][idx] * f2 + Osh[3][idx] * f3;
        rp[i] = f2bu(a * inv);
    }
    *(ushort4*)(head + (size_t)(b * LL + q0 + qq) * DA + dg) = res;
}

// ========== fused Toeplitz GEMM + proj + bias + gate (BK=64, XCD-swizzled grid) ==========
__device__ __forceinline__ void mfma_tile64(const u16* As, const u16* Bs,
                                            f32x4 acc[4][4], int wm, int wn,
                                            int l15, int q16) {
    int s7 = l15 & 7;
#pragma unroll
    for (int kk = 0; kk < 2; ++kk) {
        int j0 = kk * 4 + q16;
        bf16x8 a[4], bv[4];
#pragma unroll
        for (int i = 0; i < 4; ++i) {
            int row = wm + i * 16 + l15;
            a[i] = *(const bf16x8*)(As + (row * 8 + (j0 ^ s7)) * 8);
        }
#pragma unroll
        for (int j = 0; j < 4; ++j) {
            int row = wn + j * 16 + l15;
            bv[j] = *(const bf16x8*)(Bs + (row * 8 + (j0 ^ s7)) * 8);
        }
#pragma unroll
        for (int i = 0; i < 4; ++i)
#pragma unroll
            for (int j = 0; j < 4; ++j)
                acc[i][j] = __builtin_amdgcn_mfma_f32_16x16x32_bf16(a[i], bv[j], acc[i][j], 0, 0, 0);
    }
}

__global__ __launch_bounds__(256, 2)
void mix_kernel(const u16* __restrict__ wt,      // [512 m][512 l]
                const u16* __restrict__ vnT,     // [B][512 c][512 l]
                const u16* __restrict__ headb,   // [B][512 m][64 d]
                const u16* __restrict__ projwT,  // [512 c][64 d]
                const float* __restrict__ x,
                const float* __restrict__ tbias,
                const float* __restrict__ projb,
                float* __restrict__ out) {
    __shared__ u16 As[128 * 64];
    __shared__ u16 Bs[128 * 64];
    int lid = blockIdx.x;
    int p8 = lid & 7, rest = lid >> 3;
    int mi = rest & 3, pair = (rest >> 2) * 8 + p8;   // pair in [0,128)
    int b = pair >> 2, m0 = mi * 128, c0 = (pair & 3) * 128;
    int t = threadIdx.x, lane = t & 63, wid = t >> 6;
    int wm = (wid >> 1) * 64, wn = (wid & 1) * 64;
    int l15 = lane & 15, q16 = lane >> 4;
    f32x4 acc[4][4] = {};
    const u16* Ag = wt + (size_t)m0 * 512;
    const u16* Bg = vnT + ((size_t)b * H2 + c0) * 512;
    for (int k0 = 0; k0 < 512; k0 += 64) {       // Toeplitz phase
#pragma unroll
        for (int s = 0; s < 4; ++s) {
            int ci = t + s * 256;
            int grow = ci >> 3, gcol = ((ci & 7) ^ (grow & 7)) << 3;
            async_cp16(Ag + (size_t)grow * 512 + k0 + gcol, As + ci * 8);
            async_cp16(Bg + (size_t)grow * 512 + k0 + gcol, Bs + ci * 8);
        }
        __syncthreads();
        mfma_tile64(As, Bs, acc, wm, wn, l15, q16);
        __syncthreads();
    }
    {                                            // proj phase: single K=64 iteration
        const u16* Hg = headb + ((size_t)b * LL + m0) * DA;
        const u16* Pg = projwT + (size_t)c0 * DA;
#pragma unroll
        for (int s = 0; s < 4; ++s) {
            int ci = t + s * 256;
            int grow = ci >> 3, gcol = ((ci & 7) ^ (grow & 7)) << 3;
            async_cp16(Hg + (size_t)grow * 64 + gcol, As + ci * 8);
            async_cp16(Pg + (size_t)grow * 64 + gcol, Bs + ci * 8);
        }
        __syncthreads();
        mfma_tile64(As, Bs, acc, wm, wn, l15, q16);
        __syncthreads();
    }
    int rq = q16 * 4;
#pragma unroll
    for (int i = 0; i < 4; ++i) {
#pragma unroll
        for (int rr = 0; rr < 4; ++rr) {
            int m = m0 + wm + i * 16 + rq + rr;
            float tb = tbias[m];
            const float* xrow = x + ((size_t)b * LL + m) * HH;
            float* orow = out + ((size_t)b * LL + m) * H2;
#pragma unroll
            for (int j = 0; j < 4; ++j) {
                int c = c0 + wn + j * 16 + l15;
                float val = acc[i][j][rr] + tb + projb[c];
                orow[c] = xrow[c] * val;
            }
        }
    }
}

extern "C" void kernel_launch(void* const* d_in, const int* in_sizes, int n_in,
                              void* d_out, int out_size, void* d_ws, size_t ws_size,
                              hipStream_t stream) {
    (void)in_sizes; (void)n_in; (void)out_size; (void)ws_size;
    const float* x     = (const float*)d_in[0];
    const float* gamma = (const float*)d_in[1];
    const float* beta  = (const float*)d_in[2];
    const float* wv    = (const float*)d_in[3];
    const float* tb    = (const float*)d_in[4];
    const float* kqvw  = (const float*)d_in[5];
    const float* kqvb  = (const float*)d_in[6];
    const float* projw = (const float*)d_in[7];
    const float* projb = (const float*)d_in[8];
    float* out = (float*)d_out;

    u16* vnT_bf  = (u16*)d_ws;                          // 16 MB
    u16* qb      = vnT_bf + (size_t)NB * LL * H2;       // 2 MB
    u16* kb      = qb + (size_t)NB * LL * DA;           // 2 MB
    u16* vTb     = kb + (size_t)NB * LL * DA;           // 2 MB
    u16* head_bf = vTb + (size_t)NB * LL * DA;          // 2 MB
    u16* wt_bf   = head_bf + (size_t)NB * LL * DA;      // 512 KB
    u16* kqvwT   = wt_bf + 512 * 512;                   // 192 KB
    u16* projwT  = kqvwT + 192 * 512;                   // 64 KB

    prep_kernel <<<1536, 256, 0, stream>>>(wv, kqvw, projw, wt_bf, kqvwT, projwT);
    front_kernel<<<512, 256, 0, stream>>>(x, gamma, beta, kqvwT, kqvb,
                                          vnT_bf, qb, kb, vTb);
    attn_kernel <<<dim3(32, NB), 256, 0, stream>>>(qb, kb, vTb, head_bf);
    mix_kernel  <<<512, 256, 0, stream>>>(wt_bf, vnT_bf, head_bf, projwT,
                                          x, tb, projb, out);
}

// Round 7
// 174.308 us; speedup vs baseline: 2.1316x; 1.0116x over previous
//
#include <hip/hip_runtime.h>
#include <math.h>

#define NB 32
#define LL 512
#define HH 1024
#define H2 512
#define DA 64

typedef unsigned int u32;
typedef unsigned short u16;
typedef __bf16 bf16x8 __attribute__((ext_vector_type(8)));
typedef float f32x4 __attribute__((ext_vector_type(4)));

__device__ __forceinline__ u16 f2bu(float f) {          // fp32 -> bf16 bits, RNE
    u32 u = __builtin_bit_cast(u32, f);
    u = (u + 0x7fff + ((u >> 16) & 1)) >> 16;
    return (u16)u;
}

__device__ __forceinline__ float b2f(u16 u) {           // bf16 bits -> fp32
    u32 v = (u32)u << 16;
    return __builtin_bit_cast(float, v);
}

__device__ __forceinline__ void async_cp16(const void* g, void* l) {
    __builtin_amdgcn_global_load_lds(
        (const __attribute__((address_space(1))) u32*)g,
        (__attribute__((address_space(3))) u32*)l, 16, 0, 0);
}

// ========== prep: bf16 weight materialization (tiny, serial but short) ==========
__global__ void prep_kernel(const float* __restrict__ wv,
                            const float* __restrict__ kqvw,
                            const float* __restrict__ projw,
                            u16* __restrict__ wt, u16* __restrict__ kqvwT,
                            u16* __restrict__ projwT) {
    int e = blockIdx.x * 256 + threadIdx.x;
    if (e < 262144) {
        int m = e >> 9, l = e & 511;
        wt[e] = f2bu(wv[511 + m - l]);
    } else if (e < 262144 + 98304) {
        int i = e - 262144;
        int n = i >> 9, k = i & 511;
        kqvwT[i] = f2bu(kqvw[(size_t)k * 192 + n]);
    } else {
        int i = e - 360448;
        int c = i >> 6, d = i & 63;
        projwT[i] = f2bu(projw[(size_t)d * 512 + c]);
    }
}

// ========== front: LN + transpose + kqv GEMM, 32-row tiles, 512 blocks (2/CU) ==========
// Phase 1 writes raw bf16(v) transposed into T while accumulating LN stats (one x read);
// phase 2 applies the affine from T -> vnT with zero extra barriers.
__global__ __launch_bounds__(256, 2)
void front_kernel(const float* __restrict__ x,
                  const float* __restrict__ gamma, const float* __restrict__ beta,
                  const u16* __restrict__ kqvwT, const float* __restrict__ kqvb,
                  u16* __restrict__ vnT,
                  u16* __restrict__ qb, u16* __restrict__ kb, u16* __restrict__ vT) {
    __shared__ u16 As[32 * 72];                 // 4608 B (aliased as Ts[64][36] in epilogue)
    __shared__ u16 Bs[192 * 64];                // 24576 B (async, swizzled)
    __shared__ u16 T[512 * 34];                 // 34816 B: T[c*34+r] = bf16(v[l0+r][c])
    __shared__ float MUs[32], RSs[32];
    int blk = blockIdx.x, t = threadIdx.x;
    int b = blk >> 4, l0 = (blk & 15) * 32;
    int lane = t & 63, wid = t >> 6;
    int l15 = lane & 15, q16 = lane >> 4, q8 = q16 * 8;

    // ---- phase 0: prefetch Bs(k0=0) -- DMA overlaps the LN phase ----
#pragma unroll
    for (int s = 0; s < 6; ++s) {
        int ci = t + s * 256;
        int grow = ci >> 3, gcol = ((ci & 7) ^ (grow & 7)) << 3;
        async_cp16(kqvwT + (size_t)grow * 512 + gcol, Bs + ci * 8);
    }

    // ---- phase 1: LN stats + raw bf16 transpose write (single x pass) ----
    int r = t >> 3, q = t & 7;                  // r = local row (l), q = 64-col segment
    const float* xr = x + ((size_t)(b * LL + l0 + r)) * HH + H2;
    float s1 = 0.0f, s2 = 0.0f;
#pragma unroll
    for (int i = 0; i < 16; ++i) {
        float4 v = *(const float4*)(xr + q * 64 + i * 4);
        s1 += v.x + v.y + v.z + v.w;
        s2 += v.x * v.x + v.y * v.y + v.z * v.z + v.w * v.w;
        int c = q * 64 + i * 4;
        T[(c + 0) * 34 + r] = f2bu(v.x);
        T[(c + 1) * 34 + r] = f2bu(v.y);
        T[(c + 2) * 34 + r] = f2bu(v.z);
        T[(c + 3) * 34 + r] = f2bu(v.w);
    }
    s1 += __shfl_xor(s1, 1); s2 += __shfl_xor(s2, 1);
    s1 += __shfl_xor(s1, 2); s2 += __shfl_xor(s2, 2);
    s1 += __shfl_xor(s1, 4); s2 += __shfl_xor(s2, 4);
    float mu = s1 * (1.0f / H2);
    float rstd = rsqrtf(s2 * (1.0f / H2) - mu * mu + 1e-5f);
    if ((t & 7) == 0) { MUs[r] = mu; RSs[r] = rstd; }
    __syncthreads();

    // ---- phase 2: affine from T -> vnT (no barriers; coalesced 64B lines) ----
    {
        int cc = t >> 2, seg = t & 3;
        float m0 = MUs[seg * 8 + 0], r0s = RSs[seg * 8 + 0];
        float m1 = MUs[seg * 8 + 1], r1s = RSs[seg * 8 + 1];
        float m2 = MUs[seg * 8 + 2], r2s = RSs[seg * 8 + 2];
        float m3 = MUs[seg * 8 + 3], r3s = RSs[seg * 8 + 3];
        float m4 = MUs[seg * 8 + 4], r4s = RSs[seg * 8 + 4];
        float m5 = MUs[seg * 8 + 5], r5s = RSs[seg * 8 + 5];
        float m6 = MUs[seg * 8 + 6], r6s = RSs[seg * 8 + 6];
        float m7 = MUs[seg * 8 + 7], r7s = RSs[seg * 8 + 7];
#pragma unroll
        for (int pass = 0; pass < 8; ++pass) {
            int c = pass * 64 + cc;
            float ga = gamma[c], be = beta[c];
            const u16* Tp = T + c * 34 + seg * 8;
            ushort4 t0 = ((const ushort4*)Tp)[0];
            ushort4 t1 = ((const ushort4*)Tp)[1];
            ushort4 o0, o1;
            o0.x = f2bu((b2f(t0.x) - m0) * r0s * ga + be);
            o0.y = f2bu((b2f(t0.y) - m1) * r1s * ga + be);
            o0.z = f2bu((b2f(t0.z) - m2) * r2s * ga + be);
            o0.w = f2bu((b2f(t0.w) - m3) * r3s * ga + be);
            o1.x = f2bu((b2f(t1.x) - m4) * r4s * ga + be);
            o1.y = f2bu((b2f(t1.y) - m5) * r5s * ga + be);
            o1.z = f2bu((b2f(t1.z) - m6) * r6s * ga + be);
            o1.w = f2bu((b2f(t1.w) - m7) * r7s * ga + be);
            u16* dst = vnT + ((size_t)(b * H2 + c)) * LL + l0 + seg * 8;
            ((ushort4*)dst)[0] = o0;
            ((ushort4*)dst)[1] = o1;
        }
    }

    // ---- phase 3: kqv GEMM, M=32, N=192, BK=64 ----
    int wm = (wid & 1) * 16, wn = (wid >> 1) * 96;
    f32x4 acc[6] = {};
    for (int k0 = 0; k0 < 512; k0 += 64) {
        if (k0 > 0) {
#pragma unroll
            for (int s = 0; s < 6; ++s) {       // B: 192x64 -> 1536 chunks, swizzled
                int ci = t + s * 256;
                int grow = ci >> 3, gcol = ((ci & 7) ^ (grow & 7)) << 3;
                async_cp16(kqvwT + (size_t)grow * 512 + k0 + gcol, Bs + ci * 8);
            }
        }
#pragma unroll
        for (int s = 0; s < 2; ++s) {           // A: 32x64 fp32->bf16 (L2-hot x)
            int ci = t + s * 256;
            int row = ci >> 4, c4 = (ci & 15) * 4;
            float4 v = *(const float4*)(x + (size_t)(b * LL + l0 + row) * HH + H2 + k0 + c4);
            ushort4 p;
            p.x = f2bu(v.x); p.y = f2bu(v.y); p.z = f2bu(v.z); p.w = f2bu(v.w);
            *(ushort4*)(As + row * 72 + c4) = p;
        }
        __syncthreads();
#pragma unroll
        for (int kk = 0; kk < 2; ++kk) {
            int j0 = kk * 4 + q16;
            bf16x8 a = *(const bf16x8*)(As + (wm + l15) * 72 + kk * 32 + q8);
#pragma unroll
            for (int j = 0; j < 6; ++j) {
                int n = wn + j * 16 + l15;
                bf16x8 bb = *(const bf16x8*)(Bs + (n * 8 + (j0 ^ (n & 7))) * 8);
                acc[j] = __builtin_amdgcn_mfma_f32_16x16x32_bf16(a, bb, acc[j], 0, 0, 0);
            }
        }
        __syncthreads();
    }
    // ---- phase 4: epilogue k -> kb, q -> qb, v -> Ts transpose -> vT ----
    u16* Ts = As;                               // [64][36] = 2304 els, exact fit
    int rq = q16 * 4;
#pragma unroll
    for (int rr = 0; rr < 4; ++rr) {
        int mloc = wm + rq + rr;
        size_t mg = (size_t)(b * LL + l0 + mloc);
#pragma unroll
        for (int j = 0; j < 6; ++j) {
            int n = wn + j * 16 + l15;
            u16 hv = f2bu(acc[j][rr] + kqvb[n]);
            if (n < 64)       kb[mg * 64 + n] = hv;
            else if (n < 128) qb[mg * 64 + (n - 64)] = hv;
            else              Ts[(n - 128) * 36 + mloc] = hv;
        }
    }
    __syncthreads();
    int d = t >> 2, lo2 = (t & 3) * 8;
    u16* dst = vT + ((size_t)(b * 64 + d)) * 512 + l0 + lo2;
    const u16* src = Ts + d * 36 + lo2;
    ((ushort4*)dst)[0] = ((const ushort4*)src)[0];
    ((ushort4*)dst)[1] = ((const ushort4*)src)[1];
}

// ========== MFMA flash attention, split-K across 4 waves ==========
#define VLD 136
__global__ __launch_bounds__(256, 4)
void attn_kernel(const u16* __restrict__ qb, const u16* __restrict__ kb,
                 const u16* __restrict__ vT, u16* __restrict__ head) {
    __shared__ u16 Ps[4 * 16 * VLD];
    __shared__ float Osh[4][16 * 65];
    __shared__ float Msh[4][16], Lsh[4][16];
    int b = blockIdx.y, q0 = blockIdx.x * 16;
    int t = threadIdx.x, lane = t & 63, w = t >> 6;
    int l15 = lane & 15, q16 = lane >> 4, q8 = q16 * 8;
    int kc = w * 128;
    const u16* qg = qb + (size_t)b * LL * DA;
    const u16* kg = kb + (size_t)b * LL * DA;
    const u16* vg = vT + (size_t)b * DA * LL;

    bf16x8 aq[2];
#pragma unroll
    for (int s = 0; s < 2; ++s)
        aq[s] = *(const bf16x8*)(qg + (size_t)(q0 + l15) * DA + s * 32 + q8);

    f32x4 sc[8] = {};
#pragma unroll
    for (int j = 0; j < 8; ++j) {
#pragma unroll
        for (int s = 0; s < 2; ++s) {
            bf16x8 bk = *(const bf16x8*)(kg + (size_t)(kc + j * 16 + l15) * DA + s * 32 + q8);
            sc[j] = __builtin_amdgcn_mfma_f32_16x16x32_bf16(aq[s], bk, sc[j], 0, 0, 0);
        }
    }
    float mx[4], sm[4];
#pragma unroll
    for (int j = 0; j < 8; ++j)
#pragma unroll
        for (int rr = 0; rr < 4; ++rr) sc[j][rr] *= 0.125f;
#pragma unroll
    for (int rr = 0; rr < 4; ++rr) {
        float m0 = sc[0][rr];
#pragma unroll
        for (int j = 1; j < 8; ++j) m0 = fmaxf(m0, sc[j][rr]);
        m0 = fmaxf(m0, __shfl_xor(m0, 1));
        m0 = fmaxf(m0, __shfl_xor(m0, 2));
        m0 = fmaxf(m0, __shfl_xor(m0, 4));
        m0 = fmaxf(m0, __shfl_xor(m0, 8));
        mx[rr] = m0;
    }
#pragma unroll
    for (int j = 0; j < 8; ++j)
#pragma unroll
        for (int rr = 0; rr < 4; ++rr) sc[j][rr] = __expf(sc[j][rr] - mx[rr]);
#pragma unroll
    for (int rr = 0; rr < 4; ++rr) {
        float s0 = sc[0][rr];
#pragma unroll
        for (int j = 1; j < 8; ++j) s0 += sc[j][rr];
        s0 += __shfl_xor(s0, 1);
        s0 += __shfl_xor(s0, 2);
        s0 += __shfl_xor(s0, 4);
        s0 += __shfl_xor(s0, 8);
        sm[rr] = s0;
    }
    u16* Pw = Ps + w * 16 * VLD;
#pragma unroll
    for (int j = 0; j < 8; ++j)
#pragma unroll
        for (int rr = 0; rr < 4; ++rr)
            Pw[(q16 * 4 + rr) * VLD + j * 16 + l15] = f2bu(sc[j][rr]);
    f32x4 o[4] = {};
#pragma unroll
    for (int kt = 0; kt < 4; ++kt) {
        bf16x8 ap = *(const bf16x8*)(Pw + l15 * VLD + kt * 32 + q8);
#pragma unroll
        for (int j = 0; j < 4; ++j) {
            bf16x8 bv = *(const bf16x8*)(vg + (size_t)(j * 16 + l15) * LL + kc + kt * 32 + q8);
            o[j] = __builtin_amdgcn_mfma_f32_16x16x32_bf16(ap, bv, o[j], 0, 0, 0);
        }
    }
#pragma unroll
    for (int j = 0; j < 4; ++j)
#pragma unroll
        for (int rr = 0; rr < 4; ++rr)
            Osh[w][(q16 * 4 + rr) * 65 + j * 16 + l15] = o[j][rr];
    if (l15 == 0) {
#pragma unroll
        for (int rr = 0; rr < 4; ++rr) {
            Msh[w][q16 * 4 + rr] = mx[rr];
            Lsh[w][q16 * 4 + rr] = sm[rr];
        }
    }
    __syncthreads();
    int qq = t >> 4, dg = (t & 15) * 4;
    float m0 = Msh[0][qq], m1 = Msh[1][qq], m2 = Msh[2][qq], m3 = Msh[3][qq];
    float ms = fmaxf(fmaxf(m0, m1), fmaxf(m2, m3));
    float f0 = __expf(m0 - ms), f1 = __expf(m1 - ms), f2 = __expf(m2 - ms), f3 = __expf(m3 - ms);
    float lst = Lsh[0][qq] * f0 + Lsh[1][qq] * f1 + Lsh[2][qq] * f2 + Lsh[3][qq] * f3;
    float inv = 1.0f / lst;
    ushort4 res;
    u16* rp = (u16*)&res;
#pragma unroll
    for (int i = 0; i < 4; ++i) {
        int idx = qq * 65 + dg + i;
        float a = Osh[0][idx] * f0 + Osh[1][idx] * f1 + Osh[2][idx] * f2 + Osh[3][idx] * f3;
        rp[i] = f2bu(a * inv);
    }
    *(ushort4*)(head + (size_t)(b * LL + q0 + qq) * DA + dg) = res;
}

// ========== fused Toeplitz GEMM + proj + bias + gate (BK=64, XCD-swizzled grid) ==========
__device__ __forceinline__ void mfma_tile64(const u16* As, const u16* Bs,
                                            f32x4 acc[4][4], int wm, int wn,
                                            int l15, int q16) {
    int s7 = l15 & 7;
#pragma unroll
    for (int kk = 0; kk < 2; ++kk) {
        int j0 = kk * 4 + q16;
        bf16x8 a[4], bv[4];
#pragma unroll
        for (int i = 0; i < 4; ++i) {
            int row = wm + i * 16 + l15;
            a[i] = *(const bf16x8*)(As + (row * 8 + (j0 ^ s7)) * 8);
        }
#pragma unroll
        for (int j = 0; j < 4; ++j) {
            int row = wn + j * 16 + l15;
            bv[j] = *(const bf16x8*)(Bs + (row * 8 + (j0 ^ s7)) * 8);
        }
#pragma unroll
        for (int i = 0; i < 4; ++i)
#pragma unroll
            for (int j = 0; j < 4; ++j)
                acc[i][j] = __builtin_amdgcn_mfma_f32_16x16x32_bf16(a[i], bv[j], acc[i][j], 0, 0, 0);
    }
}

__global__ __launch_bounds__(256, 2)
void mix_kernel(const u16* __restrict__ wt,      // [512 m][512 l]
                const u16* __restrict__ vnT,     // [B][512 c][512 l]
                const u16* __restrict__ headb,   // [B][512 m][64 d]
                const u16* __restrict__ projwT,  // [512 c][64 d]
                const float* __restrict__ x,
                const float* __restrict__ tbias,
                const float* __restrict__ projb,
                float* __restrict__ out) {
    __shared__ u16 As[128 * 64];
    __shared__ u16 Bs[128 * 64];
    int lid = blockIdx.x;
    int p8 = lid & 7, rest = lid >> 3;
    int mi = rest & 3, pair = (rest >> 2) * 8 + p8;   // pair in [0,128)
    int b = pair >> 2, m0 = mi * 128, c0 = (pair & 3) * 128;
    int t = threadIdx.x, lane = t & 63, wid = t >> 6;
    int wm = (wid >> 1) * 64, wn = (wid & 1) * 64;
    int l15 = lane & 15, q16 = lane >> 4;
    f32x4 acc[4][4] = {};
    const u16* Ag = wt + (size_t)m0 * 512;
    const u16* Bg = vnT + ((size_t)b * H2 + c0) * 512;
    for (int k0 = 0; k0 < 512; k0 += 64) {       // Toeplitz phase
#pragma unroll
        for (int s = 0; s < 4; ++s) {
            int ci = t + s * 256;
            int grow = ci >> 3, gcol = ((ci & 7) ^ (grow & 7)) << 3;
            async_cp16(Ag + (size_t)grow * 512 + k0 + gcol, As + ci * 8);
            async_cp16(Bg + (size_t)grow * 512 + k0 + gcol, Bs + ci * 8);
        }
        __syncthreads();
        mfma_tile64(As, Bs, acc, wm, wn, l15, q16);
        __syncthreads();
    }
    {                                            // proj phase: single K=64 iteration
        const u16* Hg = headb + ((size_t)b * LL + m0) * DA;
        const u16* Pg = projwT + (size_t)c0 * DA;
#pragma unroll
        for (int s = 0; s < 4; ++s) {
            int ci = t + s * 256;
            int grow = ci >> 3, gcol = ((ci & 7) ^ (grow & 7)) << 3;
            async_cp16(Hg + (size_t)grow * 64 + gcol, As + ci * 8);
            async_cp16(Pg + (size_t)grow * 64 + gcol, Bs + ci * 8);
        }
        __syncthreads();
        mfma_tile64(As, Bs, acc, wm, wn, l15, q16);
        __syncthreads();
    }
    int rq = q16 * 4;
#pragma unroll
    for (int i = 0; i < 4; ++i) {
#pragma unroll
        for (int rr = 0; rr < 4; ++rr) {
            int m = m0 + wm + i * 16 + rq + rr;
            float tb = tbias[m];
            const float* xrow = x + ((size_t)b * LL + m) * HH;
            float* orow = out + ((size_t)b * LL + m) * H2;
#pragma unroll
            for (int j = 0; j < 4; ++j) {
                int c = c0 + wn + j * 16 + l15;
                float val = acc[i][j][rr] + tb + projb[c];
                orow[c] = xrow[c] * val;
            }
        }
    }
}

extern "C" void kernel_launch(void* const* d_in, const int* in_sizes, int n_in,
                              void* d_out, int out_size, void* d_ws, size_t ws_size,
                              hipStream_t stream) {
    (void)in_sizes; (void)n_in; (void)out_size; (void)ws_size;
    const float* x     = (const float*)d_in[0];
    const float* gamma = (const float*)d_in[1];
    const float* beta  = (const float*)d_in[2];
    const float* wv    = (const float*)d_in[3];
    const float* tb    = (const float*)d_in[4];
    const float* kqvw  = (const float*)d_in[5];
    const float* kqvb  = (const float*)d_in[6];
    const float* projw = (const float*)d_in[7];
    const float* projb = (const float*)d_in[8];
    float* out = (float*)d_out;

    u16* vnT_bf  = (u16*)d_ws;                          // 16 MB
    u16* qb      = vnT_bf + (size_t)NB * LL * H2;       // 2 MB
    u16* kb      = qb + (size_t)NB * LL * DA;           // 2 MB
    u16* vTb     = kb + (size_t)NB * LL * DA;           // 2 MB
    u16* head_bf = vTb + (size_t)NB * LL * DA;          // 2 MB
    u16* wt_bf   = head_bf + (size_t)NB * LL * DA;      // 512 KB
    u16* kqvwT   = wt_bf + 512 * 512;                   // 192 KB
    u16* projwT  = kqvwT + 192 * 512;                   // 64 KB

    prep_kernel <<<1536, 256, 0, stream>>>(wv, kqvw, projw, wt_bf, kqvwT, projwT);
    front_kernel<<<512, 256, 0, stream>>>(x, gamma, beta, kqvwT, kqvb,
                                          vnT_bf, qb, kb, vTb);
    attn_kernel <<<dim3(32, NB), 256, 0, stream>>>(qb, kb, vTb, head_bf);
    mix_kernel  <<<512, 256, 0, stream>>>(wt_bf, vnT_bf, head_bf, projwT,
                                          x, tb, projb, out);
}